// Round 2
// baseline (1579.985 us; speedup 1.0000x reference)
//
#include <hip/hip_runtime.h>
#include <hip/hip_bf16.h>

// MambaSpatial: B=32, C_IN=D=96, H=W=48, L=2304, K=2, N=16, R=6.
// Input/output dtype (bf16 vs f32) is detected at runtime from x's value range
// (N(0,1) data read as bf16 shows huge/NaN half-words iff the buffer is f32).
// NOTE: softmax(z, axis=1) is over a singleton axis == 1.0 -> skip path (d_in[3],d_in[4]) is dead.

typedef __hip_bfloat16 bf16;
__device__ __forceinline__ float b2f(bf16 v) { return __bfloat162float(v); }

// dtype-adaptive load (uniform predicate -> scalar branch, no speculated loads)
__device__ __forceinline__ float ldu(const void* p, int i, bool f32) {
  if (f32) return ((const float*)p)[i];
  return b2f(((const bf16*)p)[i]);
}

#define LL 2304

// ---- wbuf offsets (floats): f32-converted weights ----
#define W_IN   0        // in_proj_w [d][c] 9216
#define B_IN   9216     // 96
#define W_C2D  9312     // conv2d_w [d][9] 864
#define B_C2D  10176    // 96
#define W_LOC  10272    // local_w 864
#define B_LOC  11136    // 96
#define BN_G   11232    // 96
#define BN_B   11328    // 96
#define W_XP   11424    // x_proj_w [k][38][96] 7296
#define W_DT   18720    // dt_projs_w [k][96][6] 1152
#define B_DT   19872    // [k][96] 192
#define A2OF   20064    // -exp(A_logs)*log2(e)  [k][96][16] 3072
#define DSOF   23136    // Ds 192
#define LN_G   23328    // 96
#define LN_B   23424    // 96
#define W_OUT  23520    // out_proj_w [c][d] 9216
#define B_OUT  32736    // 96
#define WBUF_N 33024ul

// ---- workspace layout (float offsets) ----
#define O_WBUF  0ul
#define O_XFEAT (O_WBUF + WBUF_N)            // 7,077,888 ; later reused: hend / hstart
#define O_XCONV (O_XFEAT + 7077888ul)        // 7,077,888
#define O_SIM   (O_XCONV + 7077888ul)        // 73,728
#define O_SIDX  (O_SIM + 73728ul)            // 73,728 (int)
#define O_XST   (O_SIDX + 73728ul)           // xs transposed [b][l][d] 7,077,888
#define O_DT    (O_XST + 7077888ul)          // dt [b][k][l][d] 14,155,776 ; reused as ymamba
#define O_BC    (O_DT + 14155776ul)          // [b][k][l][32] (B then C) 4,718,592
#define O_DSUM  (O_BC + 4718592ul)           // [b][k][d][36] 221,184
#define O_YS    (O_DSUM + 221184ul)          // [b][k][l][d] 14,155,776
#define O_STATS (O_YS + 14155776ul)          // 192
#define O_SCSH  (O_STATS + 192ul)            // 192
#define O_FLAG  (O_SCSH + 192ul)             // 1 (dtype flag: 1.0 => f32 data)
#define O_END   (O_FLAG + 64ul)              // ~218.7 MB total

// ---------------- dtype detect: one wave probes x as bf16 ----------------
__global__ void k_detect(const void* x, float* flag) {
  int i = threadIdx.x;           // 64 threads
  bool bad = false;
  const bf16* xb = (const bf16*)x;
#pragma unroll
  for (int r = 0; r < 4; ++r) {
    float v = b2f(xb[r * 64 + i]);
    if (!(fabsf(v) <= 1e4f)) bad = true;   // catches huge and NaN
  }
  bool any = __any(bad);
  if (i == 0) flag[0] = any ? 1.f : 0.f;
}

// ---------------- prep: weights -> f32 wbuf (dtype-adaptive) ----------------
__global__ void k_prep(const void* ipw, const void* ipb, const void* c2w, const void* c2b,
                       const void* lw, const void* lb, const void* bng, const void* bnb,
                       const void* xpw, const void* dtw, const void* dtb, const void* alog,
                       const void* dss, const void* ng, const void* nb, const void* opw,
                       const void* opb, float* wb, const float* flag) {
  bool f = flag[0] > 0.5f;
  int i = blockIdx.x * 256 + threadIdx.x;
  if (i < 9216) { wb[W_IN + i] = ldu(ipw, i, f); wb[W_OUT + i] = ldu(opw, i, f); }
  if (i < 96) {
    wb[B_IN + i] = ldu(ipb, i, f); wb[B_C2D + i] = ldu(c2b, i, f); wb[B_LOC + i] = ldu(lb, i, f);
    wb[BN_G + i] = ldu(bng, i, f); wb[BN_B + i] = ldu(bnb, i, f); wb[LN_G + i] = ldu(ng, i, f);
    wb[LN_B + i] = ldu(nb, i, f); wb[B_OUT + i] = ldu(opb, i, f);
  }
  if (i < 864) { wb[W_C2D + i] = ldu(c2w, i, f); wb[W_LOC + i] = ldu(lw, i, f); }
  if (i < 7296) wb[W_XP + i] = ldu(xpw, i, f);
  if (i < 1152) wb[W_DT + i] = ldu(dtw, i, f);
  if (i < 192) { wb[B_DT + i] = ldu(dtb, i, f); wb[DSOF + i] = ldu(dss, i, f); }
  if (i < 3072) wb[A2OF + i] = -expf(ldu(alog, i, f)) * 1.4426950408889634f;
}

// ---------------- in_proj: xfeat[b][d][l] = sum_c x[b][c][l]*W[d][c] + b[d] ----------------
__global__ void k_inproj(const void* __restrict__ x, const float* __restrict__ wb,
                         float* __restrict__ xfeat, const float* __restrict__ flag) {
  int b = blockIdx.x / 9;
  int l = (blockIdx.x % 9) * 256 + threadIdx.x;
  float xv[96];
  if (flag[0] > 0.5f) {
    const float* xf = (const float*)x;
#pragma unroll
    for (int c = 0; c < 96; ++c) xv[c] = xf[(b * 96 + c) * LL + l];
  } else {
    const bf16* xb = (const bf16*)x;
#pragma unroll
    for (int c = 0; c < 96; ++c) xv[c] = b2f(xb[(b * 96 + c) * LL + l]);
  }
  for (int d = 0; d < 96; ++d) {
    const float* wr = wb + W_IN + d * 96;   // wave-uniform -> s_load
    float acc = wb[B_IN + d];
#pragma unroll
    for (int c = 0; c < 96; ++c) acc += xv[c] * wr[c];
    xfeat[(b * 96 + d) * LL + l] = acc;
  }
}

// ---------------- depthwise 3x3 SAME + bias + silu -> xconv ----------------
__global__ void k_conv_silu(const float* __restrict__ xfeat, const float* __restrict__ wb,
                            float* __restrict__ xconv) {
  int t = blockIdx.x * 256 + threadIdx.x;   // B*D*L
  int l = t % LL; int d = (t / LL) % 96; int b = t / (LL * 96);
  int h = l / 48, w = l % 48;
  const float* wr = wb + W_C2D + d * 9;
  const float* src = xfeat + (b * 96 + d) * LL;
  float acc = wb[B_C2D + d];
#pragma unroll
  for (int ki = 0; ki < 3; ++ki) {
    int hh = h + ki - 1; if (hh < 0 || hh >= 48) continue;
#pragma unroll
    for (int kj = 0; kj < 3; ++kj) {
      int ww = w + kj - 1; if (ww < 0 || ww >= 48) continue;
      acc += src[hh * 48 + ww] * wr[ki * 3 + kj];
    }
  }
  xconv[t] = acc / (1.f + expf(-acc));
}

// ---------------- cosine-sim vs center pixel (24,24) ----------------
__global__ void k_sim(const float* __restrict__ xconv, float* __restrict__ sim) {
  int b = blockIdx.x / 9;
  int l = (blockIdx.x % 9) * 256 + threadIdx.x;
  const float* base = xconv + (size_t)b * 96 * LL;
  float dot = 0, nrm = 0, cn = 0;
  for (int d = 0; d < 96; ++d) {
    float v = base[d * LL + l];
    float c = base[d * LL + 1176];   // 24*48+24, uniform -> scalar
    dot += v * c; nrm += v * v; cn += c * c;
  }
  float den = fmaxf(sqrtf(nrm), 1e-12f) * fmaxf(sqrtf(cn), 1e-12f);
  sim[b * LL + l] = dot / den;
}

// ---------------- per-batch stable argsort descending (bitonic on 64-bit keys) ----------------
__global__ void k_sort(const float* __restrict__ sim, int* __restrict__ sidx) {
  __shared__ unsigned long long key[4096];
  int b = blockIdx.x;
  for (int i = threadIdx.x; i < 4096; i += 256) {
    unsigned long long kv = ~0ull;
    if (i < LL) {
      unsigned u = __float_as_uint(sim[b * LL + i]);
      u = (u >> 31) ? ~u : (u | 0x80000000u);           // order-preserving map
      kv = (((unsigned long long)(~u)) << 32) | (unsigned)i;  // desc sim, asc idx (stable)
    }
    key[i] = kv;
  }
  __syncthreads();
  for (int k = 2; k <= 4096; k <<= 1)
    for (int j = k >> 1; j > 0; j >>= 1) {
      for (int i = threadIdx.x; i < 4096; i += 256) {
        int ij = i ^ j;
        if (ij > i) {
          unsigned long long a = key[i], c = key[ij];
          bool up = ((i & k) == 0);
          if ((a > c) == up) { key[i] = c; key[ij] = a; }
        }
      }
      __syncthreads();
    }
  for (int i = threadIdx.x; i < LL; i += 256) sidx[b * LL + i] = (int)(key[i] & 0xffffffffu);
}

// ---------------- gather sorted sequence, transposed: xst[b][l][d] ----------------
__global__ void k_gather(const float* __restrict__ xconv, const int* __restrict__ sidx,
                         float* __restrict__ xst) {
  int b = blockIdx.x / 9;
  int l = (blockIdx.x % 9) * 256 + threadIdx.x;
  int p = sidx[b * LL + l];
  const float* src = xconv + (size_t)b * 96 * LL + p;
  float* dst = xst + ((size_t)b * LL + l) * 96;
#pragma unroll
  for (int d = 0; d < 96; ++d) dst[d] = src[(size_t)d * LL];
}

// ---------------- x_dbl (38 proj) + dt projection + softplus; emit dt[b][k][l][d], BC[b][k][l][32] ----------------
__global__ void k_xdbl(const float* __restrict__ xst, const float* __restrict__ wb,
                       float* __restrict__ dt, float* __restrict__ bc) {
  int blk = blockIdx.x;
  int b = blk / 18; int k = (blk / 9) % 2; int l = (blk % 9) * 256 + threadIdx.x;
  int xrow = k ? (LL - 1 - l) : l;
  const float* src = xst + ((size_t)b * LL + xrow) * 96;
  float v[96];
#pragma unroll
  for (int d = 0; d < 96; ++d) v[d] = src[d];
  const float* wxp = wb + W_XP + k * 38 * 96;
  float r[6];
#pragma unroll
  for (int c = 0; c < 6; ++c) {
    float a = 0;
#pragma unroll
    for (int d = 0; d < 96; ++d) a += v[d] * wxp[c * 96 + d];
    r[c] = a;
  }
  float* bco = bc + ((size_t)(b * 2 + k) * LL + l) * 32;
  for (int c = 6; c < 38; ++c) {
    float a = 0;
#pragma unroll
    for (int d = 0; d < 96; ++d) a += v[d] * wxp[c * 96 + d];
    bco[c - 6] = a;
  }
  float* dto = dt + ((size_t)(b * 2 + k) * LL + l) * 96;
  for (int d = 0; d < 96; ++d) {
    const float* wd = wb + W_DT + (k * 96 + d) * 6;
    float a = wb[B_DT + k * 96 + d];
#pragma unroll
    for (int rr = 0; rr < 6; ++rr) a += r[rr] * wd[rr];
    dto[d] = (a > 20.f) ? a : log1pf(expf(a));   // softplus
  }
}

// ---------------- scan pass 1: per 64-step segment, local scan from 0 + sum(dt) ----------------
__global__ void k_scan1(const float* __restrict__ dt, const float* __restrict__ bc,
                        const float* __restrict__ xst, const float* __restrict__ wb,
                        float* __restrict__ dsum, float* __restrict__ hend) {
  int blk = blockIdx.x;                       // B*K*36
  int b = blk / 72; int k = (blk / 36) % 2; int s = blk % 36;
  int d = threadIdx.x;                        // 0..95
  float a2[16], h[16];
#pragma unroll
  for (int n = 0; n < 16; ++n) { a2[n] = wb[A2OF + (k * 96 + d) * 16 + n]; h[n] = 0.f; }
  float ds = 0.f;
  int base = (b * 2 + k) * LL + s * 64;
  for (int t = 0; t < 64; ++t) {
    int l = base + t;
    float dtv = dt[(size_t)l * 96 + d];
    int lk = k ? (LL - 1 - (s * 64 + t)) : (s * 64 + t);
    float xv = xst[((size_t)b * LL + lk) * 96 + d];
    const float* bcl = bc + (size_t)l * 32;   // uniform -> s_load
    ds += dtv;
    float dtx = dtv * xv;
#pragma unroll
    for (int n = 0; n < 16; ++n) h[n] = exp2f(dtv * a2[n]) * h[n] + dtx * bcl[n];
  }
  dsum[((b * 2 + k) * 96 + d) * 36 + s] = ds;
  float* ho = hend + ((size_t)((b * 2 + k) * 36 + s) * 96 + d) * 16;
#pragma unroll
  for (int n = 0; n < 16; ++n) ho[n] = h[n];
}

// ---------------- scan pass 2: stitch segments (exp(A*sum_dt) is the transfer coefficient) ----------------
__global__ void k_scan2(const float* __restrict__ dsum, const float* __restrict__ hend,
                        const float* __restrict__ wb, float* __restrict__ hstart) {
  int t = blockIdx.x * 256 + threadIdx.x;     // B*K*D*N = 98304
  int n = t % 16; int d = (t / 16) % 96; int k = (t / 1536) % 2; int b = t / 3072;
  float a2 = wb[A2OF + (k * 96 + d) * 16 + n];
  float h = 0.f;
  int rowd = ((b * 2 + k) * 96 + d) * 36;
  for (int s = 0; s < 36; ++s) {
    size_t idx = ((size_t)((b * 2 + k) * 36 + s) * 96 + d) * 16 + n;
    hstart[idx] = h;
    h = exp2f(a2 * dsum[rowd + s]) * h + hend[idx];
  }
}

// ---------------- scan pass 3: replay with true h0, emit ys[b][k][l][d] ----------------
__global__ void k_scan3(const float* __restrict__ dt, const float* __restrict__ bc,
                        const float* __restrict__ xst, const float* __restrict__ wb,
                        const float* __restrict__ hstart, float* __restrict__ ys) {
  int blk = blockIdx.x;
  int b = blk / 72; int k = (blk / 36) % 2; int s = blk % 36;
  int d = threadIdx.x;
  float a2[16], h[16];
#pragma unroll
  for (int n = 0; n < 16; ++n) a2[n] = wb[A2OF + (k * 96 + d) * 16 + n];
  const float* hi = hstart + ((size_t)((b * 2 + k) * 36 + s) * 96 + d) * 16;
#pragma unroll
  for (int n = 0; n < 16; ++n) h[n] = hi[n];
  float Dv = wb[DSOF + k * 96 + d];
  int base = (b * 2 + k) * LL + s * 64;
  for (int t = 0; t < 64; ++t) {
    int l = base + t;
    float dtv = dt[(size_t)l * 96 + d];
    int lk = k ? (LL - 1 - (s * 64 + t)) : (s * 64 + t);
    float xv = xst[((size_t)b * LL + lk) * 96 + d];
    const float* bcl = bc + (size_t)l * 32;
    float dtx = dtv * xv;
    float y = 0.f;
#pragma unroll
    for (int n = 0; n < 16; ++n) {
      h[n] = exp2f(dtv * a2[n]) * h[n] + dtx * bcl[n];
      y += h[n] * bcl[16 + n];
    }
    ys[(size_t)l * 96 + d] = y + Dv * xv;
  }
}

// ---------------- combine directions + inverse permutation (scatter) + channel LayerNorm ----------------
__global__ void k_combine_ln(const float* __restrict__ ys, const int* __restrict__ sidx,
                             const float* __restrict__ wb, float* __restrict__ ym) {
  int b = blockIdx.x / 9;
  int l = (blockIdx.x % 9) * 256 + threadIdx.x;
  const float* y0 = ys + ((size_t)(b * 2 + 0) * LL + l) * 96;
  const float* y1 = ys + ((size_t)(b * 2 + 1) * LL + (LL - 1 - l)) * 96;
  float v[96]; float mu = 0;
#pragma unroll
  for (int d = 0; d < 96; ++d) { v[d] = y0[d] + y1[d]; mu += v[d]; }
  mu *= (1.f / 96.f);
  float var = 0;
#pragma unroll
  for (int d = 0; d < 96; ++d) { float t = v[d] - mu; var += t * t; }
  var *= (1.f / 96.f);
  float rs = rsqrtf(var + 1e-5f);
  int p = sidx[b * LL + l];
  float* o = ym + ((size_t)b * LL + p) * 96;
#pragma unroll
  for (int d = 0; d < 96; ++d) o[d] = (v[d] - mu) * rs * wb[LN_G + d] + wb[LN_B + d];
}

// ---------------- batchnorm stats for local conv (recomputed, not materialized) ----------------
__global__ void k_bnstats(const float* __restrict__ xconv, const float* __restrict__ wb,
                          float* __restrict__ stats) {
  int b = blockIdx.x / 96; int d = blockIdx.x % 96;
  const float* src = xconv + (size_t)(b * 96 + d) * LL;
  const float* wr = wb + W_LOC + d * 9;
  float bias = wb[B_LOC + d];
  float s1 = 0, s2 = 0;
  for (int l = threadIdx.x; l < LL; l += 256) {
    int h = l / 48, w = l % 48;
    float acc = bias;
#pragma unroll
    for (int ki = 0; ki < 3; ++ki) {
      int hh = h + ki - 1; if (hh < 0 || hh >= 48) continue;
#pragma unroll
      for (int kj = 0; kj < 3; ++kj) {
        int ww = w + kj - 1; if (ww < 0 || ww >= 48) continue;
        acc += src[hh * 48 + ww] * wr[ki * 3 + kj];
      }
    }
    s1 += acc; s2 += acc * acc;
  }
  __shared__ float r1[256], r2[256];
  r1[threadIdx.x] = s1; r2[threadIdx.x] = s2; __syncthreads();
  for (int o = 128; o > 0; o >>= 1) {
    if (threadIdx.x < o) { r1[threadIdx.x] += r1[threadIdx.x + o]; r2[threadIdx.x] += r2[threadIdx.x + o]; }
    __syncthreads();
  }
  if (threadIdx.x == 0) { atomicAdd(&stats[d], r1[0]); atomicAdd(&stats[96 + d], r2[0]); }
}

__global__ void k_bnfin(const float* __restrict__ stats, const float* __restrict__ wb,
                        float* __restrict__ scsh) {
  int d = threadIdx.x; if (d >= 96) return;
  float mean = stats[d] * (1.f / 73728.f);
  float var = stats[96 + d] * (1.f / 73728.f) - mean * mean;
  float sc = wb[BN_G + d] * rsqrtf(var + 1e-5f);
  scsh[d] = sc; scsh[96 + d] = wb[BN_B + d] - mean * sc;
}

// ---------------- final: local conv + BN + silu, add mamba, out_proj, dtype-adaptive store ----------------
__global__ void k_final(const float* __restrict__ xconv, const float* __restrict__ ym,
                        const float* __restrict__ wb, const float* __restrict__ scsh,
                        void* __restrict__ out, const float* __restrict__ flag) {
  int b = blockIdx.x / 9;
  int l = (blockIdx.x % 9) * 256 + threadIdx.x;
  int h = l / 48, w = l % 48;
  const float* ymr = ym + ((size_t)b * LL + l) * 96;
  float v[96];
  for (int d = 0; d < 96; ++d) {
    const float* src = xconv + (size_t)(b * 96 + d) * LL;
    const float* wr = wb + W_LOC + d * 9;
    float acc = wb[B_LOC + d];
#pragma unroll
    for (int ki = 0; ki < 3; ++ki) {
      int hh = h + ki - 1; if (hh < 0 || hh >= 48) continue;
#pragma unroll
      for (int kj = 0; kj < 3; ++kj) {
        int ww = w + kj - 1; if (ww < 0 || ww >= 48) continue;
        acc += src[hh * 48 + ww] * wr[ki * 3 + kj];
      }
    }
    float lc = acc * scsh[d] + scsh[96 + d];
    v[d] = ymr[d] + lc / (1.f + expf(-lc));
  }
  bool f = flag[0] > 0.5f;
  for (int c = 0; c < 96; ++c) {
    const float* wr = wb + W_OUT + c * 96;
    float acc = wb[B_OUT + c];
#pragma unroll
    for (int d = 0; d < 96; ++d) acc += v[d] * wr[d];
    int oi = (b * 96 + c) * LL + l;
    if (f) ((float*)out)[oi] = acc;
    else   ((bf16*)out)[oi] = __float2bfloat16(acc);
  }
}

extern "C" void kernel_launch(void* const* d_in, const int* in_sizes, int n_in,
                              void* d_out, int out_size, void* d_ws, size_t ws_size,
                              hipStream_t stream) {
  if (ws_size < O_END * sizeof(float)) return;   // need ~219 MB scratch
  float* ws = (float*)d_ws;
  float* wb    = ws + O_WBUF;
  float* xfeat = ws + O_XFEAT;
  float* xconv = ws + O_XCONV;
  float* sim   = ws + O_SIM;
  int*   sidx  = (int*)(ws + O_SIDX);
  float* xst   = ws + O_XST;
  float* dt    = ws + O_DT;
  float* bc    = ws + O_BC;
  float* dsum  = ws + O_DSUM;
  float* ysb   = ws + O_YS;
  float* stats = ws + O_STATS;
  float* scsh  = ws + O_SCSH;
  float* flag  = ws + O_FLAG;
  float* hend   = xfeat;               // xfeat dead after conv; 2*3,538,944 fits exactly
  float* hstart = xfeat + 3538944ul;
  float* ym     = dt;                  // dt dead after scan3

  k_detect<<<1, 64, 0, stream>>>(d_in[0], flag);
  k_prep<<<36, 256, 0, stream>>>(
      d_in[1], d_in[2], d_in[5], d_in[6], d_in[7], d_in[8], d_in[9], d_in[10],
      d_in[11], d_in[12], d_in[13], d_in[14], d_in[15], d_in[16], d_in[17], d_in[18],
      d_in[19], wb, flag);
  k_inproj<<<288, 256, 0, stream>>>(d_in[0], wb, xfeat, flag);
  k_conv_silu<<<27648, 256, 0, stream>>>(xfeat, wb, xconv);
  k_sim<<<288, 256, 0, stream>>>(xconv, sim);
  k_sort<<<32, 256, 0, stream>>>(sim, sidx);
  k_gather<<<288, 256, 0, stream>>>(xconv, sidx, xst);
  k_xdbl<<<576, 256, 0, stream>>>(xst, wb, dt, bc);
  k_scan1<<<2304, 96, 0, stream>>>(dt, bc, xst, wb, dsum, hend);
  k_scan2<<<384, 256, 0, stream>>>(dsum, hend, wb, hstart);
  k_scan3<<<2304, 96, 0, stream>>>(dt, bc, xst, wb, hstart, ysb);
  k_combine_ln<<<288, 256, 0, stream>>>(ysb, sidx, wb, ym);
  hipMemsetAsync(stats, 0, 192 * sizeof(float), stream);
  k_bnstats<<<3072, 256, 0, stream>>>(xconv, wb, stats);
  k_bnfin<<<1, 96, 0, stream>>>(stats, wb, scsh);
  k_final<<<288, 256, 0, stream>>>(xconv, ym, wb, scsh, d_out, flag);
}

// Round 3
// 949.179 us; speedup vs baseline: 1.6646x; 1.6646x over previous
//
#include <hip/hip_runtime.h>
#include <hip/hip_bf16.h>

// MambaSpatial: B=32, C_IN=D=96, H=W=48, L=2304, K=2, N=16, R=6.
// Input/output dtype (bf16 vs f32) detected at runtime from x's value range.
// softmax(z, axis=1) over singleton axis == 1.0 -> skip path (d_in[3],d_in[4]) dead.
// R2 lesson: no __launch_bounds__ => 64-VGPR cap => v[96] arrays spill to scratch
// (k_inproj WRITE_SIZE 96MB vs 28MB real). All per-pixel kernels now use
// __launch_bounds__(256,2) (VGPR cap 256) + fully const-indexed local arrays.

typedef __hip_bfloat16 bf16;
__device__ __forceinline__ float b2f(bf16 v) { return __bfloat162float(v); }

__device__ __forceinline__ float ldu(const void* p, int i, bool f32) {
  if (f32) return ((const float*)p)[i];
  return b2f(((const bf16*)p)[i]);
}

#define LL 2304

// ---- wbuf offsets (floats) ----
#define W_IN   0
#define B_IN   9216
#define W_C2D  9312
#define B_C2D  10176
#define W_LOC  10272
#define B_LOC  11136
#define BN_G   11232
#define BN_B   11328
#define W_XP   11424
#define W_DT   18720
#define B_DT   19872
#define A2OF   20064
#define DSOF   23136
#define LN_G   23328
#define LN_B   23424
#define W_OUT  23520
#define B_OUT  32736
#define WBUF_N 33024ul

// ---- workspace layout (float offsets) ----
#define O_WBUF  0ul
#define O_XFEAT (O_WBUF + WBUF_N)            // 7,077,888 ; reused: hend/hstart, then lcbuf
#define O_XCONV (O_XFEAT + 7077888ul)
#define O_SIM   (O_XCONV + 7077888ul)
#define O_SIDX  (O_SIM + 73728ul)
#define O_XST   (O_SIDX + 73728ul)           // [b][l][d]
#define O_DT    (O_XST + 7077888ul)          // [b][k][l][d] ; reused as ym
#define O_BC    (O_DT + 14155776ul)          // [b][k][l][32]
#define O_DSUM  (O_BC + 4718592ul)
#define O_YS    (O_DSUM + 221184ul)          // [b][k][l][d]
#define O_STATS (O_YS + 14155776ul)
#define O_SCSH  (O_STATS + 192ul)
#define O_FLAG  (O_SCSH + 192ul)
#define O_END   (O_FLAG + 64ul)

// ---------------- dtype detect ----------------
__global__ void k_detect(const void* x, float* flag) {
  int i = threadIdx.x;
  bool bad = false;
  const bf16* xb = (const bf16*)x;
#pragma unroll
  for (int r = 0; r < 4; ++r) {
    float v = b2f(xb[r * 64 + i]);
    if (!(fabsf(v) <= 1e4f)) bad = true;
  }
  bool any = __any(bad);
  if (i == 0) flag[0] = any ? 1.f : 0.f;
}

// ---------------- prep: weights -> f32 ----------------
__global__ void k_prep(const void* ipw, const void* ipb, const void* c2w, const void* c2b,
                       const void* lw, const void* lb, const void* bng, const void* bnb,
                       const void* xpw, const void* dtw, const void* dtb, const void* alog,
                       const void* dss, const void* ng, const void* nb, const void* opw,
                       const void* opb, float* wb, const float* flag) {
  bool f = flag[0] > 0.5f;
  int i = blockIdx.x * 256 + threadIdx.x;
  if (i < 9216) { wb[W_IN + i] = ldu(ipw, i, f); wb[W_OUT + i] = ldu(opw, i, f); }
  if (i < 96) {
    wb[B_IN + i] = ldu(ipb, i, f); wb[B_C2D + i] = ldu(c2b, i, f); wb[B_LOC + i] = ldu(lb, i, f);
    wb[BN_G + i] = ldu(bng, i, f); wb[BN_B + i] = ldu(bnb, i, f); wb[LN_G + i] = ldu(ng, i, f);
    wb[LN_B + i] = ldu(nb, i, f); wb[B_OUT + i] = ldu(opb, i, f);
  }
  if (i < 864) { wb[W_C2D + i] = ldu(c2w, i, f); wb[W_LOC + i] = ldu(lw, i, f); }
  if (i < 7296) wb[W_XP + i] = ldu(xpw, i, f);
  if (i < 1152) wb[W_DT + i] = ldu(dtw, i, f);
  if (i < 192) { wb[B_DT + i] = ldu(dtb, i, f); wb[DSOF + i] = ldu(dss, i, f); }
  if (i < 3072) wb[A2OF + i] = -expf(ldu(alog, i, f)) * 1.4426950408889634f;
}

// ---------------- in_proj ----------------
__global__ __launch_bounds__(256, 2)
void k_inproj(const void* __restrict__ x, const float* __restrict__ wb,
              float* __restrict__ xfeat, const float* __restrict__ flag) {
  int b = blockIdx.x / 9;
  int l = (blockIdx.x % 9) * 256 + threadIdx.x;
  float xv[96];
  if (flag[0] > 0.5f) {
    const float* xf = (const float*)x;
#pragma unroll
    for (int c = 0; c < 96; ++c) xv[c] = xf[(b * 96 + c) * LL + l];
  } else {
    const bf16* xb = (const bf16*)x;
#pragma unroll
    for (int c = 0; c < 96; ++c) xv[c] = b2f(xb[(b * 96 + c) * LL + l]);
  }
  for (int d = 0; d < 96; ++d) {
    const float* wr = wb + W_IN + d * 96;   // wave-uniform -> s_load
    float acc = wb[B_IN + d];
#pragma unroll
    for (int c = 0; c < 96; ++c) acc += xv[c] * wr[c];
    xfeat[(b * 96 + d) * LL + l] = acc;
  }
}

// ---------------- depthwise 3x3 + bias + silu ----------------
__global__ void k_conv_silu(const float* __restrict__ xfeat, const float* __restrict__ wb,
                            float* __restrict__ xconv) {
  int t = blockIdx.x * 256 + threadIdx.x;
  int l = t % LL; int d = (t / LL) % 96; int b = t / (LL * 96);
  int h = l / 48, w = l % 48;
  const float* wr = wb + W_C2D + d * 9;
  const float* src = xfeat + (b * 96 + d) * LL;
  float acc = wb[B_C2D + d];
#pragma unroll
  for (int ki = 0; ki < 3; ++ki) {
    int hh = h + ki - 1; if (hh < 0 || hh >= 48) continue;
#pragma unroll
    for (int kj = 0; kj < 3; ++kj) {
      int ww = w + kj - 1; if (ww < 0 || ww >= 48) continue;
      acc += src[hh * 48 + ww] * wr[ki * 3 + kj];
    }
  }
  xconv[t] = acc / (1.f + expf(-acc));
}

// ---------------- depthwise 3x3 local conv + bias (no act) -> lcbuf[b][d][l] ----------------
__global__ void k_conv_lc(const float* __restrict__ xconv, const float* __restrict__ wb,
                          float* __restrict__ lcbuf) {
  int t = blockIdx.x * 256 + threadIdx.x;
  int l = t % LL; int d = (t / LL) % 96; int b = t / (LL * 96);
  int h = l / 48, w = l % 48;
  const float* wr = wb + W_LOC + d * 9;
  const float* src = xconv + (b * 96 + d) * LL;
  float acc = wb[B_LOC + d];
#pragma unroll
  for (int ki = 0; ki < 3; ++ki) {
    int hh = h + ki - 1; if (hh < 0 || hh >= 48) continue;
#pragma unroll
    for (int kj = 0; kj < 3; ++kj) {
      int ww = w + kj - 1; if (ww < 0 || ww >= 48) continue;
      acc += src[hh * 48 + ww] * wr[ki * 3 + kj];
    }
  }
  lcbuf[t] = acc;
}

// ---------------- cosine-sim vs center pixel ----------------
__global__ void k_sim(const float* __restrict__ xconv, float* __restrict__ sim) {
  int b = blockIdx.x / 9;
  int l = (blockIdx.x % 9) * 256 + threadIdx.x;
  const float* base = xconv + (size_t)b * 96 * LL;
  float dot = 0, nrm = 0, cn = 0;
  for (int d = 0; d < 96; ++d) {
    float v = base[d * LL + l];
    float c = base[d * LL + 1176];
    dot += v * c; nrm += v * v; cn += c * c;
  }
  float den = fmaxf(sqrtf(nrm), 1e-12f) * fmaxf(sqrtf(cn), 1e-12f);
  sim[b * LL + l] = dot / den;
}

// ---------------- per-batch stable argsort desc (bitonic, 1024 threads) ----------------
__global__ void k_sort(const float* __restrict__ sim, int* __restrict__ sidx) {
  __shared__ unsigned long long key[4096];
  int b = blockIdx.x;
  for (int i = threadIdx.x; i < 4096; i += 1024) {
    unsigned long long kv = ~0ull;
    if (i < LL) {
      unsigned u = __float_as_uint(sim[b * LL + i]);
      u = (u >> 31) ? ~u : (u | 0x80000000u);
      kv = (((unsigned long long)(~u)) << 32) | (unsigned)i;
    }
    key[i] = kv;
  }
  __syncthreads();
  for (int k = 2; k <= 4096; k <<= 1)
    for (int j = k >> 1; j > 0; j >>= 1) {
      for (int i = threadIdx.x; i < 4096; i += 1024) {
        int ij = i ^ j;
        if (ij > i) {
          unsigned long long a = key[i], c = key[ij];
          bool up = ((i & k) == 0);
          if ((a > c) == up) { key[i] = c; key[ij] = a; }
        }
      }
      __syncthreads();
    }
  for (int i = threadIdx.x; i < LL; i += 1024) sidx[b * LL + i] = (int)(key[i] & 0xffffffffu);
}

// ---------------- gather: 32 lanes per pixel, coalesced 128B writes ----------------
__global__ void k_gather(const float* __restrict__ xconv, const int* __restrict__ sidx,
                         float* __restrict__ xst) {
  int g = blockIdx.x * 8 + (threadIdx.x >> 5);   // pixel index in [0, B*LL)
  int lane = threadIdx.x & 31;
  int b = g / LL, l = g % LL;
  int p = sidx[b * LL + l];
  const float* src = xconv + (size_t)b * 96 * LL + p;
  float* dst = xst + ((size_t)b * LL + l) * 96;
#pragma unroll
  for (int i = 0; i < 3; ++i) {
    int d = lane + 32 * i;
    dst[d] = src[(size_t)d * LL];
  }
}

// ---------------- x_dbl + dt proj + softplus ----------------
__global__ __launch_bounds__(256, 2)
void k_xdbl(const float* __restrict__ xst, const float* __restrict__ wb,
            float* __restrict__ dt, float* __restrict__ bc) {
  int blk = blockIdx.x;
  int b = blk / 18; int k = (blk / 9) % 2; int l = (blk % 9) * 256 + threadIdx.x;
  int xrow = k ? (LL - 1 - l) : l;
  const float4* s4 = (const float4*)(xst + ((size_t)b * LL + xrow) * 96);
  float v[96];
#pragma unroll
  for (int i = 0; i < 24; ++i) {
    float4 t = s4[i];
    v[4 * i] = t.x; v[4 * i + 1] = t.y; v[4 * i + 2] = t.z; v[4 * i + 3] = t.w;
  }
  const float* wxp = wb + W_XP + k * 38 * 96;
  float r[6];
#pragma unroll
  for (int c = 0; c < 6; ++c) {
    float a = 0;
#pragma unroll
    for (int d = 0; d < 96; ++d) a += v[d] * wxp[c * 96 + d];
    r[c] = a;
  }
  float bcl[32];
#pragma unroll
  for (int c = 6; c < 38; ++c) {
    float a = 0;
#pragma unroll
    for (int d = 0; d < 96; ++d) a += v[d] * wxp[c * 96 + d];
    bcl[c - 6] = a;
  }
  float4* bco4 = (float4*)(bc + ((size_t)(b * 2 + k) * LL + l) * 32);
#pragma unroll
  for (int i = 0; i < 8; ++i)
    bco4[i] = make_float4(bcl[4 * i], bcl[4 * i + 1], bcl[4 * i + 2], bcl[4 * i + 3]);
  float dtl[96];
#pragma unroll
  for (int d = 0; d < 96; ++d) {
    const float* wd = wb + W_DT + (k * 96 + d) * 6;
    float a = wb[B_DT + k * 96 + d];
#pragma unroll
    for (int rr = 0; rr < 6; ++rr) a += r[rr] * wd[rr];
    dtl[d] = (a > 20.f) ? a : log1pf(expf(a));
  }
  float4* dto4 = (float4*)(dt + ((size_t)(b * 2 + k) * LL + l) * 96);
#pragma unroll
  for (int i = 0; i < 24; ++i)
    dto4[i] = make_float4(dtl[4 * i], dtl[4 * i + 1], dtl[4 * i + 2], dtl[4 * i + 3]);
}

// ---------------- scan pass 1 ----------------
__global__ void k_scan1(const float* __restrict__ dt, const float* __restrict__ bc,
                        const float* __restrict__ xst, const float* __restrict__ wb,
                        float* __restrict__ dsum, float* __restrict__ hend) {
  int blk = blockIdx.x;
  int b = blk / 72; int k = (blk / 36) % 2; int s = blk % 36;
  int d = threadIdx.x;
  float a2[16], h[16];
#pragma unroll
  for (int n = 0; n < 16; ++n) { a2[n] = wb[A2OF + (k * 96 + d) * 16 + n]; h[n] = 0.f; }
  float ds = 0.f;
  int base = (b * 2 + k) * LL + s * 64;
  for (int t = 0; t < 64; ++t) {
    int l = base + t;
    float dtv = dt[(size_t)l * 96 + d];
    int lk = k ? (LL - 1 - (s * 64 + t)) : (s * 64 + t);
    float xv = xst[((size_t)b * LL + lk) * 96 + d];
    const float* bcl = bc + (size_t)l * 32;   // uniform -> s_load
    ds += dtv;
    float dtx = dtv * xv;
#pragma unroll
    for (int n = 0; n < 16; ++n) h[n] = exp2f(dtv * a2[n]) * h[n] + dtx * bcl[n];
  }
  dsum[((b * 2 + k) * 96 + d) * 36 + s] = ds;
  float* ho = hend + ((size_t)((b * 2 + k) * 36 + s) * 96 + d) * 16;
#pragma unroll
  for (int n = 0; n < 16; ++n) ho[n] = h[n];
}

// ---------------- scan pass 2: stitch ----------------
__global__ void k_scan2(const float* __restrict__ dsum, const float* __restrict__ hend,
                        const float* __restrict__ wb, float* __restrict__ hstart) {
  int t = blockIdx.x * 256 + threadIdx.x;
  int n = t % 16; int d = (t / 16) % 96; int k = (t / 1536) % 2; int b = t / 3072;
  float a2 = wb[A2OF + (k * 96 + d) * 16 + n];
  float h = 0.f;
  int rowd = ((b * 2 + k) * 96 + d) * 36;
  for (int s = 0; s < 36; ++s) {
    size_t idx = ((size_t)((b * 2 + k) * 36 + s) * 96 + d) * 16 + n;
    hstart[idx] = h;
    h = exp2f(a2 * dsum[rowd + s]) * h + hend[idx];
  }
}

// ---------------- scan pass 3: replay, emit ys ----------------
__global__ void k_scan3(const float* __restrict__ dt, const float* __restrict__ bc,
                        const float* __restrict__ xst, const float* __restrict__ wb,
                        const float* __restrict__ hstart, float* __restrict__ ys) {
  int blk = blockIdx.x;
  int b = blk / 72; int k = (blk / 36) % 2; int s = blk % 36;
  int d = threadIdx.x;
  float a2[16], h[16];
#pragma unroll
  for (int n = 0; n < 16; ++n) a2[n] = wb[A2OF + (k * 96 + d) * 16 + n];
  const float* hi = hstart + ((size_t)((b * 2 + k) * 36 + s) * 96 + d) * 16;
#pragma unroll
  for (int n = 0; n < 16; ++n) h[n] = hi[n];
  float Dv = wb[DSOF + k * 96 + d];
  int base = (b * 2 + k) * LL + s * 64;
  for (int t = 0; t < 64; ++t) {
    int l = base + t;
    float dtv = dt[(size_t)l * 96 + d];
    int lk = k ? (LL - 1 - (s * 64 + t)) : (s * 64 + t);
    float xv = xst[((size_t)b * LL + lk) * 96 + d];
    const float* bcl = bc + (size_t)l * 32;
    float dtx = dtv * xv;
    float y = 0.f;
#pragma unroll
    for (int n = 0; n < 16; ++n) {
      h[n] = exp2f(dtv * a2[n]) * h[n] + dtx * bcl[n];
      y += h[n] * bcl[16 + n];
    }
    ys[(size_t)l * 96 + d] = y + Dv * xv;
  }
}

// ---------------- combine + unpermute + LayerNorm ----------------
__global__ __launch_bounds__(256, 2)
void k_combine_ln(const float* __restrict__ ys, const int* __restrict__ sidx,
                  const float* __restrict__ wb, float* __restrict__ ym) {
  int b = blockIdx.x / 9;
  int l = (blockIdx.x % 9) * 256 + threadIdx.x;
  const float4* y04 = (const float4*)(ys + ((size_t)(b * 2 + 0) * LL + l) * 96);
  const float4* y14 = (const float4*)(ys + ((size_t)(b * 2 + 1) * LL + (LL - 1 - l)) * 96);
  float v[96]; float mu = 0;
#pragma unroll
  for (int i = 0; i < 24; ++i) {
    float4 a = y04[i], c = y14[i];
    v[4 * i] = a.x + c.x; v[4 * i + 1] = a.y + c.y;
    v[4 * i + 2] = a.z + c.z; v[4 * i + 3] = a.w + c.w;
    mu += v[4 * i] + v[4 * i + 1] + v[4 * i + 2] + v[4 * i + 3];
  }
  mu *= (1.f / 96.f);
  float var = 0;
#pragma unroll
  for (int d = 0; d < 96; ++d) { float t = v[d] - mu; var += t * t; }
  var *= (1.f / 96.f);
  float rs = rsqrtf(var + 1e-5f);
  int p = sidx[b * LL + l];
  float4* o4 = (float4*)(ym + ((size_t)b * LL + p) * 96);
#pragma unroll
  for (int i = 0; i < 24; ++i) {
    float4 t;
    t.x = (v[4 * i] - mu) * rs * wb[LN_G + 4 * i] + wb[LN_B + 4 * i];
    t.y = (v[4 * i + 1] - mu) * rs * wb[LN_G + 4 * i + 1] + wb[LN_B + 4 * i + 1];
    t.z = (v[4 * i + 2] - mu) * rs * wb[LN_G + 4 * i + 2] + wb[LN_B + 4 * i + 2];
    t.w = (v[4 * i + 3] - mu) * rs * wb[LN_G + 4 * i + 3] + wb[LN_B + 4 * i + 3];
    o4[i] = t;
  }
}

// ---------------- batchnorm stats over lcbuf ----------------
__global__ void k_bnstats(const float* __restrict__ lcbuf, float* __restrict__ stats) {
  int b = blockIdx.x / 96; int d = blockIdx.x % 96;
  const float* src = lcbuf + (size_t)(b * 96 + d) * LL;
  float s1 = 0, s2 = 0;
  for (int l = threadIdx.x; l < LL; l += 256) {
    float a = src[l];
    s1 += a; s2 += a * a;
  }
  __shared__ float r1[256], r2[256];
  r1[threadIdx.x] = s1; r2[threadIdx.x] = s2; __syncthreads();
  for (int o = 128; o > 0; o >>= 1) {
    if (threadIdx.x < o) { r1[threadIdx.x] += r1[threadIdx.x + o]; r2[threadIdx.x] += r2[threadIdx.x + o]; }
    __syncthreads();
  }
  if (threadIdx.x == 0) { atomicAdd(&stats[d], r1[0]); atomicAdd(&stats[96 + d], r2[0]); }
}

__global__ void k_bnfin(const float* __restrict__ stats, const float* __restrict__ wb,
                        float* __restrict__ scsh) {
  int d = threadIdx.x; if (d >= 96) return;
  float mean = stats[d] * (1.f / 73728.f);
  float var = stats[96 + d] * (1.f / 73728.f) - mean * mean;
  float sc = wb[BN_G + d] * rsqrtf(var + 1e-5f);
  scsh[d] = sc; scsh[96 + d] = wb[BN_B + d] - mean * sc;
}

// ---------------- final: BN+silu(lc) + ym, out_proj, store ----------------
__global__ __launch_bounds__(256, 2)
void k_final(const float* __restrict__ lcbuf, const float* __restrict__ ym,
             const float* __restrict__ wb, const float* __restrict__ scsh,
             void* __restrict__ out, const float* __restrict__ flag) {
  int b = blockIdx.x / 9;
  int l = (blockIdx.x % 9) * 256 + threadIdx.x;
  float v[96];
#pragma unroll
  for (int d = 0; d < 96; ++d) {
    float lc = lcbuf[(size_t)(b * 96 + d) * LL + l] * scsh[d] + scsh[96 + d];
    v[d] = lc / (1.f + expf(-lc));
  }
  const float4* ym4 = (const float4*)(ym + ((size_t)b * LL + l) * 96);
#pragma unroll
  for (int i = 0; i < 24; ++i) {
    float4 t = ym4[i];
    v[4 * i] += t.x; v[4 * i + 1] += t.y; v[4 * i + 2] += t.z; v[4 * i + 3] += t.w;
  }
  bool f = flag[0] > 0.5f;
  for (int c = 0; c < 96; ++c) {
    const float* wr = wb + W_OUT + c * 96;   // uniform -> s_load
    float acc = wb[B_OUT + c];
#pragma unroll
    for (int d = 0; d < 96; ++d) acc += v[d] * wr[d];
    int oi = (b * 96 + c) * LL + l;
    if (f) ((float*)out)[oi] = acc;
    else   ((bf16*)out)[oi] = __float2bfloat16(acc);
  }
}

extern "C" void kernel_launch(void* const* d_in, const int* in_sizes, int n_in,
                              void* d_out, int out_size, void* d_ws, size_t ws_size,
                              hipStream_t stream) {
  if (ws_size < O_END * sizeof(float)) return;
  float* ws = (float*)d_ws;
  float* wb    = ws + O_WBUF;
  float* xfeat = ws + O_XFEAT;
  float* xconv = ws + O_XCONV;
  float* sim   = ws + O_SIM;
  int*   sidx  = (int*)(ws + O_SIDX);
  float* xst   = ws + O_XST;
  float* dt    = ws + O_DT;
  float* bc    = ws + O_BC;
  float* dsum  = ws + O_DSUM;
  float* ysb   = ws + O_YS;
  float* stats = ws + O_STATS;
  float* scsh  = ws + O_SCSH;
  float* flag  = ws + O_FLAG;
  float* hend   = xfeat;               // xfeat dead after conv
  float* hstart = xfeat + 3538944ul;
  float* lcbuf  = xfeat;               // hend/hstart dead after scan3
  float* ym     = dt;                  // dt dead after scan3

  k_detect<<<1, 64, 0, stream>>>(d_in[0], flag);
  k_prep<<<36, 256, 0, stream>>>(
      d_in[1], d_in[2], d_in[5], d_in[6], d_in[7], d_in[8], d_in[9], d_in[10],
      d_in[11], d_in[12], d_in[13], d_in[14], d_in[15], d_in[16], d_in[17], d_in[18],
      d_in[19], wb, flag);
  k_inproj<<<288, 256, 0, stream>>>(d_in[0], wb, xfeat, flag);
  k_conv_silu<<<27648, 256, 0, stream>>>(xfeat, wb, xconv);
  k_sim<<<288, 256, 0, stream>>>(xconv, sim);
  k_sort<<<32, 1024, 0, stream>>>(sim, sidx);
  k_gather<<<9216, 256, 0, stream>>>(xconv, sidx, xst);
  k_xdbl<<<576, 256, 0, stream>>>(xst, wb, dt, bc);
  k_scan1<<<2304, 96, 0, stream>>>(dt, bc, xst, wb, dsum, hend);
  k_scan2<<<384, 256, 0, stream>>>(dsum, hend, wb, hstart);
  k_scan3<<<2304, 96, 0, stream>>>(dt, bc, xst, wb, hstart, ysb);
  k_combine_ln<<<288, 256, 0, stream>>>(ysb, sidx, wb, ym);
  k_conv_lc<<<27648, 256, 0, stream>>>(xconv, wb, lcbuf);
  hipMemsetAsync(stats, 0, 192 * sizeof(float), stream);
  k_bnstats<<<3072, 256, 0, stream>>>(lcbuf, stats);
  k_bnfin<<<1, 96, 0, stream>>>(stats, wb, scsh);
  k_final<<<288, 256, 0, stream>>>(lcbuf, ym, wb, scsh, d_out, flag);
}

// Round 4
// 802.427 us; speedup vs baseline: 1.9690x; 1.1829x over previous
//
#include <hip/hip_runtime.h>
#include <hip/hip_bf16.h>

// MambaSpatial: B=32, C_IN=D=96, H=W=48, L=2304, K=2, N=16, R=6.
// R3 lessons: per-lane row reads (lane owns a [96]-float row) are TA-bound
// (64 lines/instr). All GEMM-ish kernels are now accumulator-major streaming
// from d-major buffers (coalesced lane=l). dt is never materialized (rank-6
// r stored instead; softplus in-scan). A = -(1..16) (checked at runtime) =>
// dA_n = sigmoid(-a)^(n+1): 16 exps/step -> 1 exp + 1 log1p + 1 rcp + 15 mul.
// scan3+combine+LN fused (ys eliminated).

typedef __hip_bfloat16 bf16;
__device__ __forceinline__ float b2f(bf16 v) { return __bfloat162float(v); }
__device__ __forceinline__ float ldu(const void* p, int i, bool f32) {
  if (f32) return ((const float*)p)[i];
  return b2f(((const bf16*)p)[i]);
}

#define LL 2304

// ---- wbuf offsets (floats) ----
#define W_INT  0        // in_proj_w transposed [c][d] 9216
#define B_IN   9216
#define W_C2D  9312     // conv2d_w [d][9] 864
#define B_C2D  10176
#define W_LOC  10272
#define B_LOC  11136
#define BN_G   11232
#define BN_B   11328
#define W_XPT  11424    // x_proj_w transposed [d_src][80]: [0..37]=k0 c, [38..75]=k1 c ; 7680
#define W_DT   19104    // dt_projs_w [k][d][6] 1152
#define B_DT   20256    // [k][d] 192
#define A2OF   20448    // -exp(A_logs)*log2(e) [k][d][16] 3072 (slow path)
#define DSOF   23520    // Ds 192
#define LN_G   23712
#define LN_B   23808
#define W_OUTT 23904    // out_proj_w transposed [d][c] 9216
#define B_OUT  33120
#define WBUF_N 33280ul

// ---- workspace layout (float offsets) ----
#define O_WBUF  0ul
#define O_XFEAT 33280ul        // 7,077,888 ; reused: hend/hstart ; then ym_dm
#define O_XCONV 7111168ul      // 7,077,888
#define O_SIM   14189056ul     // 73,728
#define O_SIDX  14262784ul     // 73,728 (int)
#define O_XST   14336512ul     // sorted l-major [b][l][d] 7,077,888 ; reused: lcbuf
#define O_XSTD  21414400ul     // sorted d-major [b][d][l] 7,077,888
#define O_RBUF  28492288ul     // [b][k][l][8] 1,179,648
#define O_BC    29671936ul     // [b][k][l][32] 4,718,592
#define O_DSUM  34390528ul     // [b][k][d][36] 221,184
#define O_YMLM  34611712ul     // ym l-major [b][p][96] 7,077,888
#define O_STATS 41689600ul     // 192
#define O_AFLG  41689792ul     // 64 (A-structure violation counter; 0 => fast path)
#define O_SCSH  41689856ul     // 192
#define O_FLAG  41690048ul     // 64 (dtype flag)
#define O_END   41690112ul     // ~166.8 MB

// ---------------- dtype detect ----------------
__global__ void k_detect(const void* x, float* flag) {
  int i = threadIdx.x;
  bool bad = false;
  const bf16* xb = (const bf16*)x;
#pragma unroll
  for (int r = 0; r < 4; ++r) {
    float v = b2f(xb[r * 64 + i]);
    if (!(fabsf(v) <= 1e4f)) bad = true;
  }
  bool any = __any(bad);
  if (i == 0) flag[0] = any ? 1.f : 0.f;
}

// ---------------- prep: weights -> f32 (with transposes) ----------------
__global__ void k_prep(const void* ipw, const void* ipb, const void* c2w, const void* c2b,
                       const void* lw, const void* lb, const void* bng, const void* bnb,
                       const void* xpw, const void* dtw, const void* dtb, const void* alog,
                       const void* dss, const void* ng, const void* nb, const void* opw,
                       const void* opb, float* wb, const float* flag, float* aflag) {
  bool f = flag[0] > 0.5f;
  int i = blockIdx.x * 256 + threadIdx.x;
  if (i < 9216) {
    int r = i / 96, c = i % 96;
    wb[W_INT + c * 96 + r] = ldu(ipw, i, f);    // in_proj [d][c] -> [c][d]
    wb[W_OUTT + c * 96 + r] = ldu(opw, i, f);   // out_proj [c][d] -> [d][c]
  }
  if (i < 96) {
    wb[B_IN + i] = ldu(ipb, i, f); wb[B_C2D + i] = ldu(c2b, i, f); wb[B_LOC + i] = ldu(lb, i, f);
    wb[BN_G + i] = ldu(bng, i, f); wb[BN_B + i] = ldu(bnb, i, f); wb[LN_G + i] = ldu(ng, i, f);
    wb[LN_B + i] = ldu(nb, i, f); wb[B_OUT + i] = ldu(opb, i, f);
  }
  if (i < 864) { wb[W_C2D + i] = ldu(c2w, i, f); wb[W_LOC + i] = ldu(lw, i, f); }
  if (i < 7296) {           // x_proj_w [k][38][96] -> [d][80]
    int k = i / 3648, c = (i / 96) % 38, d = i % 96;
    wb[W_XPT + d * 80 + k * 38 + c] = ldu(xpw, i, f);
  }
  if (i < 1152) wb[W_DT + i] = ldu(dtw, i, f);
  if (i < 192) { wb[B_DT + i] = ldu(dtb, i, f); wb[DSOF + i] = ldu(dss, i, f); }
  if (i < 3072) {
    float av = expf(ldu(alog, i, f));
    wb[A2OF + i] = -av * 1.4426950408889634f;
    int n = i % 16;
    if (fabsf(av - (float)(n + 1)) > 1e-3f * (n + 1)) atomicAdd(aflag, 1.f);
  }
}

// ---------------- in_proj (acc-major, d-split x2) ----------------
__global__ __launch_bounds__(256, 4)
void k_inproj(const void* __restrict__ x, const float* __restrict__ wb,
              float* __restrict__ xfeat, const float* __restrict__ flag) {
  int b = blockIdx.x / 18;
  int half = (blockIdx.x / 9) % 2;
  int l = (blockIdx.x % 9) * 256 + threadIdx.x;
  float acc[48];
#pragma unroll
  for (int j = 0; j < 48; ++j) acc[j] = wb[B_IN + half * 48 + j];
  bool f = flag[0] > 0.5f;
  if (f) {
    const float* xf = (const float*)x;
    for (int c = 0; c < 96; ++c) {
      float xc = xf[(b * 96 + c) * LL + l];
      const float* wr = wb + W_INT + c * 96 + half * 48;
#pragma unroll
      for (int j = 0; j < 48; ++j) acc[j] += xc * wr[j];
    }
  } else {
    const bf16* xb = (const bf16*)x;
    for (int c = 0; c < 96; ++c) {
      float xc = b2f(xb[(b * 96 + c) * LL + l]);
      const float* wr = wb + W_INT + c * 96 + half * 48;
#pragma unroll
      for (int j = 0; j < 48; ++j) acc[j] += xc * wr[j];
    }
  }
#pragma unroll
  for (int j = 0; j < 48; ++j) xfeat[(b * 96 + half * 48 + j) * LL + l] = acc[j];
}

// ---------------- depthwise 3x3 + bias + silu ----------------
__global__ __launch_bounds__(256, 8)
void k_conv_silu(const float* __restrict__ xfeat, const float* __restrict__ wb,
                 float* __restrict__ xconv) {
  int t = blockIdx.x * 256 + threadIdx.x;
  int l = t % LL; int d = (t / LL) % 96; int b = t / (LL * 96);
  int h = l / 48, w = l % 48;
  const float* wr = wb + W_C2D + d * 9;
  const float* src = xfeat + (b * 96 + d) * LL;
  float acc = wb[B_C2D + d];
#pragma unroll
  for (int ki = 0; ki < 3; ++ki) {
    int hh = h + ki - 1; if (hh < 0 || hh >= 48) continue;
#pragma unroll
    for (int kj = 0; kj < 3; ++kj) {
      int ww = w + kj - 1; if (ww < 0 || ww >= 48) continue;
      acc += src[hh * 48 + ww] * wr[ki * 3 + kj];
    }
  }
  xconv[t] = acc / (1.f + expf(-acc));
}

// ---------------- depthwise 3x3 local conv + bias -> lcbuf ----------------
__global__ __launch_bounds__(256, 8)
void k_conv_lc(const float* __restrict__ xconv, const float* __restrict__ wb,
               float* __restrict__ lcbuf) {
  int t = blockIdx.x * 256 + threadIdx.x;
  int l = t % LL; int d = (t / LL) % 96; int b = t / (LL * 96);
  int h = l / 48, w = l % 48;
  const float* wr = wb + W_LOC + d * 9;
  const float* src = xconv + (b * 96 + d) * LL;
  float acc = wb[B_LOC + d];
#pragma unroll
  for (int ki = 0; ki < 3; ++ki) {
    int hh = h + ki - 1; if (hh < 0 || hh >= 48) continue;
#pragma unroll
    for (int kj = 0; kj < 3; ++kj) {
      int ww = w + kj - 1; if (ww < 0 || ww >= 48) continue;
      acc += src[hh * 48 + ww] * wr[ki * 3 + kj];
    }
  }
  lcbuf[t] = acc;
}

// ---------------- cosine-sim vs center pixel ----------------
__global__ __launch_bounds__(256, 8)
void k_sim(const float* __restrict__ xconv, float* __restrict__ sim) {
  int b = blockIdx.x / 9;
  int l = (blockIdx.x % 9) * 256 + threadIdx.x;
  const float* base = xconv + (size_t)b * 96 * LL;
  float dot = 0, nrm = 0, cn = 0;
  for (int d = 0; d < 96; ++d) {
    float v = base[d * LL + l];
    float c = base[d * LL + 1176];
    dot += v * c; nrm += v * v; cn += c * c;
  }
  float den = fmaxf(sqrtf(nrm), 1e-12f) * fmaxf(sqrtf(cn), 1e-12f);
  sim[b * LL + l] = dot / den;
}

// ---------------- per-batch stable argsort desc (bitonic) ----------------
__global__ void k_sort(const float* __restrict__ sim, int* __restrict__ sidx) {
  __shared__ unsigned long long key[4096];
  int b = blockIdx.x;
  for (int i = threadIdx.x; i < 4096; i += 1024) {
    unsigned long long kv = ~0ull;
    if (i < LL) {
      unsigned u = __float_as_uint(sim[b * LL + i]);
      u = (u >> 31) ? ~u : (u | 0x80000000u);
      kv = (((unsigned long long)(~u)) << 32) | (unsigned)i;
    }
    key[i] = kv;
  }
  __syncthreads();
  for (int k = 2; k <= 4096; k <<= 1)
    for (int j = k >> 1; j > 0; j >>= 1) {
      for (int i = threadIdx.x; i < 4096; i += 1024) {
        int ij = i ^ j;
        if (ij > i) {
          unsigned long long a = key[i], c = key[ij];
          bool up = ((i & k) == 0);
          if ((a > c) == up) { key[i] = c; key[ij] = a; }
        }
      }
      __syncthreads();
    }
  for (int i = threadIdx.x; i < LL; i += 1024) sidx[b * LL + i] = (int)(key[i] & 0xffffffffu);
}

// ---------------- gather sorted sequence (l-major) ----------------
__global__ __launch_bounds__(256, 8)
void k_gather(const float* __restrict__ xconv, const int* __restrict__ sidx,
              float* __restrict__ xst) {
  int g = blockIdx.x * 8 + (threadIdx.x >> 5);
  int lane = threadIdx.x & 31;
  int b = g / LL, l = g % LL;
  int p = sidx[b * LL + l];
  const float* src = xconv + (size_t)b * 96 * LL + p;
  float* dst = xst + ((size_t)b * LL + l) * 96;
#pragma unroll
  for (int i = 0; i < 3; ++i) {
    int d = lane + 32 * i;
    dst[d] = src[(size_t)d * LL];
  }
}

// ---------------- transpose per-b: [2304][96] -> [96][2304] ----------------
__global__ __launch_bounds__(256, 4)
void k_transpose(const float* __restrict__ in, float* __restrict__ out) {
  __shared__ float tile[64 * 97];
  int b = blockIdx.x / 36;
  int l0 = (blockIdx.x % 36) * 64;
#pragma unroll
  for (int it = 0; it < 24; ++it) {
    int idx = it * 256 + threadIdx.x;
    int r = idx / 96, c = idx % 96;
    tile[r * 97 + c] = in[((size_t)b * LL + l0 + r) * 96 + c];
  }
  __syncthreads();
#pragma unroll
  for (int it = 0; it < 24; ++it) {
    int idx = it * 256 + threadIdx.x;
    int d = idx / 64, j = idx % 64;
    out[((size_t)b * 96 + d) * LL + l0 + j] = tile[j * 97 + d];
  }
}

// ---------------- x_dbl for one direction (acc-major) ----------------
template <int KSEL>
__global__ __launch_bounds__(256, 4)
void k_xdbl(const float* __restrict__ xstd, const float* __restrict__ wb,
            float* __restrict__ rbuf, float* __restrict__ bc) {
  int b = blockIdx.x / 9;
  int l = (blockIdx.x % 9) * 256 + threadIdx.x;
  float acc[38];
#pragma unroll
  for (int j = 0; j < 38; ++j) acc[j] = 0.f;
  for (int c = 0; c < 96; ++c) {
    float xc = xstd[((size_t)b * 96 + c) * LL + l];
    const float* wr = wb + W_XPT + c * 80 + KSEL * 38;   // uniform -> s_load
#pragma unroll
    for (int j = 0; j < 38; ++j) acc[j] += xc * wr[j];
  }
  int lout = KSEL ? (LL - 1 - l) : l;
  float4* r4 = (float4*)(rbuf + ((size_t)(b * 2 + KSEL) * LL + lout) * 8);
  r4[0] = make_float4(acc[0], acc[1], acc[2], acc[3]);
  r4[1] = make_float4(acc[4], acc[5], 0.f, 0.f);
  float4* b4 = (float4*)(bc + ((size_t)(b * 2 + KSEL) * LL + lout) * 32);
#pragma unroll
  for (int i = 0; i < 8; ++i)
    b4[i] = make_float4(acc[6 + 4 * i], acc[7 + 4 * i], acc[8 + 4 * i], acc[9 + 4 * i]);
}

// ---------------- scan pass 1 (dt on the fly) ----------------
__global__ __launch_bounds__(96, 4)
void k_scan1(const float* __restrict__ rbuf, const float* __restrict__ bc,
             const float* __restrict__ xst, const float* __restrict__ wb,
             float* __restrict__ dsum, float* __restrict__ hend,
             const float* __restrict__ aflag) {
  int blk = blockIdx.x;
  int b = blk / 72; int k = (blk / 36) % 2; int s = blk % 36;
  int d = threadIdx.x;
  float wd[6];
#pragma unroll
  for (int j = 0; j < 6; ++j) wd[j] = wb[W_DT + (k * 96 + d) * 6 + j];
  float bd = wb[B_DT + k * 96 + d];
  float h[16];
#pragma unroll
  for (int n = 0; n < 16; ++n) h[n] = 0.f;
  float ds = 0.f;
  int base = (b * 2 + k) * LL + s * 64;
  bool fast = aflag[0] == 0.f;
  if (fast) {
    for (int t = 0; t < 64; ++t) {
      int l = base + t;
      const float* rr = rbuf + (size_t)l * 8;     // uniform -> s_load
      float a = bd + rr[0] * wd[0] + rr[1] * wd[1] + rr[2] * wd[2]
                   + rr[3] * wd[3] + rr[4] * wd[4] + rr[5] * wd[5];
      float ea = expf(a);
      float dtv = (a > 20.f) ? a : log1pf(ea);
      ds += dtv;
      int lk = k ? (LL - 1 - (s * 64 + t)) : (s * 64 + t);
      float xv = xst[((size_t)b * LL + lk) * 96 + d];
      float dtx = dtv * xv;
      const float* bcl = bc + (size_t)l * 32;     // uniform -> s_load
      float p1 = 1.f / (1.f + ea);                // exp(-dt)
      float p2 = p1 * p1, p3 = p2 * p1, p4 = p2 * p2, p5 = p4 * p1, p6 = p4 * p2,
            p7 = p4 * p3, p8 = p4 * p4, p9 = p8 * p1, p10 = p8 * p2, p11 = p8 * p3,
            p12 = p8 * p4, p13 = p8 * p5, p14 = p8 * p6, p15 = p8 * p7, p16 = p8 * p8;
      h[0] = p1 * h[0] + dtx * bcl[0];   h[1] = p2 * h[1] + dtx * bcl[1];
      h[2] = p3 * h[2] + dtx * bcl[2];   h[3] = p4 * h[3] + dtx * bcl[3];
      h[4] = p5 * h[4] + dtx * bcl[4];   h[5] = p6 * h[5] + dtx * bcl[5];
      h[6] = p7 * h[6] + dtx * bcl[6];   h[7] = p8 * h[7] + dtx * bcl[7];
      h[8] = p9 * h[8] + dtx * bcl[8];   h[9] = p10 * h[9] + dtx * bcl[9];
      h[10] = p11 * h[10] + dtx * bcl[10]; h[11] = p12 * h[11] + dtx * bcl[11];
      h[12] = p13 * h[12] + dtx * bcl[12]; h[13] = p14 * h[13] + dtx * bcl[13];
      h[14] = p15 * h[14] + dtx * bcl[14]; h[15] = p16 * h[15] + dtx * bcl[15];
    }
  } else {
    float a2[16];
#pragma unroll
    for (int n = 0; n < 16; ++n) a2[n] = wb[A2OF + (k * 96 + d) * 16 + n];
    for (int t = 0; t < 64; ++t) {
      int l = base + t;
      const float* rr = rbuf + (size_t)l * 8;
      float a = bd + rr[0] * wd[0] + rr[1] * wd[1] + rr[2] * wd[2]
                   + rr[3] * wd[3] + rr[4] * wd[4] + rr[5] * wd[5];
      float dtv = (a > 20.f) ? a : log1pf(expf(a));
      ds += dtv;
      int lk = k ? (LL - 1 - (s * 64 + t)) : (s * 64 + t);
      float xv = xst[((size_t)b * LL + lk) * 96 + d];
      float dtx = dtv * xv;
      const float* bcl = bc + (size_t)l * 32;
#pragma unroll
      for (int n = 0; n < 16; ++n) h[n] = exp2f(dtv * a2[n]) * h[n] + dtx * bcl[n];
    }
  }
  dsum[((b * 2 + k) * 96 + d) * 36 + s] = ds;
  float* ho = hend + ((size_t)((b * 2 + k) * 36 + s) * 96 + d) * 16;
#pragma unroll
  for (int n = 0; n < 16; ++n) ho[n] = h[n];
}

// ---------------- scan pass 2: stitch ----------------
__global__ __launch_bounds__(256, 4)
void k_scan2(const float* __restrict__ dsum, const float* __restrict__ hend,
             const float* __restrict__ wb, float* __restrict__ hstart) {
  int t = blockIdx.x * 256 + threadIdx.x;
  int n = t % 16; int d = (t / 16) % 96; int k = (t / 1536) % 2; int b = t / 3072;
  float a2 = wb[A2OF + (k * 96 + d) * 16 + n];
  float h = 0.f;
  int rowd = ((b * 2 + k) * 96 + d) * 36;
  for (int s = 0; s < 36; ++s) {
    size_t idx = ((size_t)((b * 2 + k) * 36 + s) * 96 + d) * 16 + n;
    hstart[idx] = h;
    h = exp2f(a2 * dsum[rowd + s]) * h + hend[idx];
  }
}

// ---------------- scan3 + combine + LN fused ----------------
__global__ __launch_bounds__(192, 4)
void k_scan3ln(const float* __restrict__ rbuf, const float* __restrict__ bc,
               const float* __restrict__ xst, const float* __restrict__ wb,
               const float* __restrict__ hstart, const int* __restrict__ sidx,
               float* __restrict__ ymlm, const float* __restrict__ aflag) {
  __shared__ float yA[64 * 97];
  __shared__ float yB[64 * 97];
  __shared__ float smu[64], srs[64];
  int b = blockIdx.x / 36;
  int s = blockIdx.x % 36;
  int t = threadIdx.x;
  {
    int sub = (t < 96) ? 0 : 1;           // sub==k
    int d = t - sub * 96;
    int k = sub;
    int seg = sub ? (35 - s) : s;
    float* yacc = sub ? yB : yA;
    float wd[6];
#pragma unroll
    for (int j = 0; j < 6; ++j) wd[j] = wb[W_DT + (k * 96 + d) * 6 + j];
    float bd = wb[B_DT + k * 96 + d];
    float Dv = wb[DSOF + k * 96 + d];
    float h[16];
    const float* hi = hstart + ((size_t)((b * 2 + k) * 36 + seg) * 96 + d) * 16;
#pragma unroll
    for (int n = 0; n < 16; ++n) h[n] = hi[n];
    int base = (b * 2 + k) * LL + seg * 64;
    bool fast = aflag[0] == 0.f;
    if (fast) {
      for (int i = 0; i < 64; ++i) {
        int l = base + i;
        const float* rr = rbuf + (size_t)l * 8;
        float a = bd + rr[0] * wd[0] + rr[1] * wd[1] + rr[2] * wd[2]
                     + rr[3] * wd[3] + rr[4] * wd[4] + rr[5] * wd[5];
        float ea = expf(a);
        float dtv = (a > 20.f) ? a : log1pf(ea);
        int lk = k ? (LL - 1 - (seg * 64 + i)) : (seg * 64 + i);
        float xv = xst[((size_t)b * LL + lk) * 96 + d];
        float dtx = dtv * xv;
        const float* bcl = bc + (size_t)l * 32;
        float p1 = 1.f / (1.f + ea);
        float p2 = p1 * p1, p3 = p2 * p1, p4 = p2 * p2, p5 = p4 * p1, p6 = p4 * p2,
              p7 = p4 * p3, p8 = p4 * p4, p9 = p8 * p1, p10 = p8 * p2, p11 = p8 * p3,
              p12 = p8 * p4, p13 = p8 * p5, p14 = p8 * p6, p15 = p8 * p7, p16 = p8 * p8;
        float y;
        h[0] = p1 * h[0] + dtx * bcl[0];   y  = h[0] * bcl[16];
        h[1] = p2 * h[1] + dtx * bcl[1];   y += h[1] * bcl[17];
        h[2] = p3 * h[2] + dtx * bcl[2];   y += h[2] * bcl[18];
        h[3] = p4 * h[3] + dtx * bcl[3];   y += h[3] * bcl[19];
        h[4] = p5 * h[4] + dtx * bcl[4];   y += h[4] * bcl[20];
        h[5] = p6 * h[5] + dtx * bcl[5];   y += h[5] * bcl[21];
        h[6] = p7 * h[6] + dtx * bcl[6];   y += h[6] * bcl[22];
        h[7] = p8 * h[7] + dtx * bcl[7];   y += h[7] * bcl[23];
        h[8] = p9 * h[8] + dtx * bcl[8];   y += h[8] * bcl[24];
        h[9] = p10 * h[9] + dtx * bcl[9];  y += h[9] * bcl[25];
        h[10] = p11 * h[10] + dtx * bcl[10]; y += h[10] * bcl[26];
        h[11] = p12 * h[11] + dtx * bcl[11]; y += h[11] * bcl[27];
        h[12] = p13 * h[12] + dtx * bcl[12]; y += h[12] * bcl[28];
        h[13] = p14 * h[13] + dtx * bcl[13]; y += h[13] * bcl[29];
        h[14] = p15 * h[14] + dtx * bcl[14]; y += h[14] * bcl[30];
        h[15] = p16 * h[15] + dtx * bcl[15]; y += h[15] * bcl[31];
        int qloc = k ? (63 - i) : i;
        yacc[qloc * 97 + d] = y + Dv * xv;
      }
    } else {
      float a2[16];
#pragma unroll
      for (int n = 0; n < 16; ++n) a2[n] = wb[A2OF + (k * 96 + d) * 16 + n];
      for (int i = 0; i < 64; ++i) {
        int l = base + i;
        const float* rr = rbuf + (size_t)l * 8;
        float a = bd + rr[0] * wd[0] + rr[1] * wd[1] + rr[2] * wd[2]
                     + rr[3] * wd[3] + rr[4] * wd[4] + rr[5] * wd[5];
        float dtv = (a > 20.f) ? a : log1pf(expf(a));
        int lk = k ? (LL - 1 - (seg * 64 + i)) : (seg * 64 + i);
        float xv = xst[((size_t)b * LL + lk) * 96 + d];
        float dtx = dtv * xv;
        const float* bcl = bc + (size_t)l * 32;
        float y = 0.f;
#pragma unroll
        for (int n = 0; n < 16; ++n) {
          h[n] = exp2f(dtv * a2[n]) * h[n] + dtx * bcl[n];
          y += h[n] * bcl[16 + n];
        }
        int qloc = k ? (63 - i) : i;
        yacc[qloc * 97 + d] = y + Dv * xv;
      }
    }
  }
  __syncthreads();
  // LN stats: one thread per row
  if (t < 64) {
    float sum = 0, ss = 0;
#pragma unroll
    for (int d = 0; d < 96; ++d) {
      float v = yA[t * 97 + d] + yB[t * 97 + d];
      sum += v; ss += v * v;
    }
    float mu = sum * (1.f / 96.f);
    float var = ss * (1.f / 96.f) - mu * mu;
    smu[t] = mu;
    srs[t] = rsqrtf(var + 1e-5f);
  }
  __syncthreads();
  // write: 3 threads per row, 32 channels each
  {
    int r = t / 3, c0 = (t % 3) * 32;
    int q = s * 64 + r;
    int p = sidx[b * LL + q];
    float mu = smu[r], rs = srs[r];
    float4* o4 = (float4*)(ymlm + ((size_t)b * LL + p) * 96 + c0);
#pragma unroll
    for (int i = 0; i < 8; ++i) {
      int dd = c0 + 4 * i;
      float4 o;
      o.x = (yA[r * 97 + dd] + yB[r * 97 + dd] - mu) * rs * wb[LN_G + dd] + wb[LN_B + dd];
      o.y = (yA[r * 97 + dd + 1] + yB[r * 97 + dd + 1] - mu) * rs * wb[LN_G + dd + 1] + wb[LN_B + dd + 1];
      o.z = (yA[r * 97 + dd + 2] + yB[r * 97 + dd + 2] - mu) * rs * wb[LN_G + dd + 2] + wb[LN_B + dd + 2];
      o.w = (yA[r * 97 + dd + 3] + yB[r * 97 + dd + 3] - mu) * rs * wb[LN_B ? LN_G + dd + 3 : LN_G + dd + 3] + wb[LN_B + dd + 3];
      o4[i] = o;
    }
  }
}

// ---------------- batchnorm stats ----------------
__global__ __launch_bounds__(256, 8)
void k_bnstats(const float* __restrict__ lcbuf, float* __restrict__ stats) {
  int b = blockIdx.x / 96; int d = blockIdx.x % 96;
  const float* src = lcbuf + (size_t)(b * 96 + d) * LL;
  float s1 = 0, s2 = 0;
  for (int l = threadIdx.x; l < LL; l += 256) {
    float a = src[l];
    s1 += a; s2 += a * a;
  }
  __shared__ float r1[256], r2[256];
  r1[threadIdx.x] = s1; r2[threadIdx.x] = s2; __syncthreads();
  for (int o = 128; o > 0; o >>= 1) {
    if (threadIdx.x < o) { r1[threadIdx.x] += r1[threadIdx.x + o]; r2[threadIdx.x] += r2[threadIdx.x + o]; }
    __syncthreads();
  }
  if (threadIdx.x == 0) { atomicAdd(&stats[d], r1[0]); atomicAdd(&stats[96 + d], r2[0]); }
}

__global__ void k_bnfin(const float* __restrict__ stats, const float* __restrict__ wb,
                        float* __restrict__ scsh) {
  int d = threadIdx.x; if (d >= 96) return;
  float mean = stats[d] * (1.f / 73728.f);
  float var = stats[96 + d] * (1.f / 73728.f) - mean * mean;
  float sc = wb[BN_G + d] * rsqrtf(var + 1e-5f);
  scsh[d] = sc; scsh[96 + d] = wb[BN_B + d] - mean * sc;
}

// ---------------- final (acc-major, c-split x2) ----------------
__global__ __launch_bounds__(256, 4)
void k_final(const float* __restrict__ lcbuf, const float* __restrict__ ymdm,
             const float* __restrict__ wb, const float* __restrict__ scsh,
             void* __restrict__ out, const float* __restrict__ flag) {
  int b = blockIdx.x / 18;
  int half = (blockIdx.x / 9) % 2;
  int l = (blockIdx.x % 9) * 256 + threadIdx.x;
  float acc[48];
#pragma unroll
  for (int j = 0; j < 48; ++j) acc[j] = wb[B_OUT + half * 48 + j];
  for (int d = 0; d < 96; ++d) {
    float lc = lcbuf[((size_t)b * 96 + d) * LL + l] * scsh[d] + scsh[96 + d];
    float vd = lc / (1.f + expf(-lc)) + ymdm[((size_t)b * 96 + d) * LL + l];
    const float* wr = wb + W_OUTT + d * 96 + half * 48;   // uniform -> s_load
#pragma unroll
    for (int j = 0; j < 48; ++j) acc[j] += vd * wr[j];
  }
  bool f = flag[0] > 0.5f;
  if (f) {
    float* of = (float*)out;
#pragma unroll
    for (int j = 0; j < 48; ++j) of[(b * 96 + half * 48 + j) * LL + l] = acc[j];
  } else {
    bf16* ob = (bf16*)out;
#pragma unroll
    for (int j = 0; j < 48; ++j) ob[(b * 96 + half * 48 + j) * LL + l] = __float2bfloat16(acc[j]);
  }
}

extern "C" void kernel_launch(void* const* d_in, const int* in_sizes, int n_in,
                              void* d_out, int out_size, void* d_ws, size_t ws_size,
                              hipStream_t stream) {
  if (ws_size < O_END * sizeof(float)) return;
  float* ws = (float*)d_ws;
  float* wb    = ws + O_WBUF;
  float* xfeat = ws + O_XFEAT;
  float* xconv = ws + O_XCONV;
  float* sim   = ws + O_SIM;
  int*   sidx  = (int*)(ws + O_SIDX);
  float* xst   = ws + O_XST;
  float* xstd  = ws + O_XSTD;
  float* rbuf  = ws + O_RBUF;
  float* bc    = ws + O_BC;
  float* dsum  = ws + O_DSUM;
  float* ymlm  = ws + O_YMLM;
  float* stats = ws + O_STATS;
  float* aflag = ws + O_AFLG;
  float* scsh  = ws + O_SCSH;
  float* flag  = ws + O_FLAG;
  float* hend   = xfeat;                 // xfeat dead after conv_silu
  float* hstart = xfeat + 3538944ul;
  float* ymdm   = xfeat;                 // hend/hstart dead after scan3ln
  float* lcbuf  = xst;                   // xst dead after scan3ln

  hipMemsetAsync(stats, 0, 256 * sizeof(float), stream);   // stats + aflag
  k_detect<<<1, 64, 0, stream>>>(d_in[0], flag);
  k_prep<<<36, 256, 0, stream>>>(
      d_in[1], d_in[2], d_in[5], d_in[6], d_in[7], d_in[8], d_in[9], d_in[10],
      d_in[11], d_in[12], d_in[13], d_in[14], d_in[15], d_in[16], d_in[17], d_in[18],
      d_in[19], wb, flag, aflag);
  k_inproj<<<576, 256, 0, stream>>>(d_in[0], wb, xfeat, flag);
  k_conv_silu<<<27648, 256, 0, stream>>>(xfeat, wb, xconv);
  k_sim<<<288, 256, 0, stream>>>(xconv, sim);
  k_sort<<<32, 1024, 0, stream>>>(sim, sidx);
  k_gather<<<9216, 256, 0, stream>>>(xconv, sidx, xst);
  k_transpose<<<1152, 256, 0, stream>>>(xst, xstd);
  k_xdbl<0><<<288, 256, 0, stream>>>(xstd, wb, rbuf, bc);
  k_xdbl<1><<<288, 256, 0, stream>>>(xstd, wb, rbuf, bc);
  k_scan1<<<2304, 96, 0, stream>>>(rbuf, bc, xst, wb, dsum, hend, aflag);
  k_scan2<<<384, 256, 0, stream>>>(dsum, hend, wb, hstart);
  k_scan3ln<<<1152, 192, 0, stream>>>(rbuf, bc, xst, wb, hstart, sidx, ymlm, aflag);
  k_transpose<<<1152, 256, 0, stream>>>(ymlm, ymdm);
  k_conv_lc<<<27648, 256, 0, stream>>>(xconv, wb, lcbuf);
  k_bnstats<<<3072, 256, 0, stream>>>(lcbuf, stats);
  k_bnfin<<<1, 96, 0, stream>>>(stats, wb, scsh);
  k_final<<<576, 256, 0, stream>>>(lcbuf, ymdm, wb, scsh, d_out, flag);
}

// Round 5
// 662.913 us; speedup vs baseline: 2.3834x; 1.2105x over previous
//
#include <hip/hip_runtime.h>
#include <hip/hip_bf16.h>

// MambaSpatial: B=32, C_IN=D=96, H=W=48, L=2304, K=2, N=16, R=6.
// R4 lessons: scan kernels are latency-bound (serial steps x per-step scalar
// loads, occupancy capped by LDS). Now: 32-step segments (S=72), bc/rbuf
// LDS-staged per segment, 192-thr full-wave scan blocks, k0/k1 segment pairing
// gives 32-row LN tiles (half the y-LDS). Gather goes d-major-first (L1-row
// random reads) + LDS transpose. conv_lc fused with bnstats.

typedef __hip_bfloat16 bf16;
__device__ __forceinline__ float b2f(bf16 v) { return __bfloat162float(v); }
__device__ __forceinline__ float ldu(const void* p, int i, bool f32) {
  if (f32) return ((const float*)p)[i];
  return b2f(((const bf16*)p)[i]);
}

#define LL 2304
#define NSEG 72          // 32-step segments

// ---- wbuf offsets (floats) ----
#define W_INT  0        // in_proj_w transposed [c][d] 9216
#define B_IN   9216
#define W_C2D  9312
#define B_C2D  10176
#define W_LOC  10272
#define B_LOC  11136
#define BN_G   11232
#define BN_B   11328
#define W_XPT  11424    // x_proj_w transposed [d][80]
#define W_DT   19104    // dt_projs_w [k][d][6]
#define B_DT   20256
#define A2OF   20448    // -exp(A_logs)*log2(e) [k][d][16]
#define DSOF   23520
#define LN_G   23712
#define LN_B   23808
#define W_OUTT 23904    // out_proj_w transposed [d][c]
#define B_OUT  33120
#define WBUF_N 33280ul

// ---- workspace layout (float offsets) ----
#define O_WBUF  0ul
#define O_XFEAT 33280ul        // 7,077,888 ; reused: hend ; then ymdm
#define O_XCONV 7111168ul      // 7,077,888
#define O_SIM   14189056ul
#define O_SIDX  14262784ul
#define O_XST   14336512ul     // sorted l-major [b][l][d] ; reused: lcbuf
#define O_XSTD  21414400ul     // sorted d-major [b][d][l] ; reused: hstart
#define O_RBUF  28492288ul     // [b][k][l][8]
#define O_BC    29671936ul     // [b][k][l][32]
#define O_DSUM  34390528ul     // [b][k][d][72] 442,368
#define O_YMLM  34832896ul     // [b][p][96] 7,077,888
#define O_STATS 41910784ul
#define O_AFLG  41910976ul
#define O_SCSH  41911040ul
#define O_FLAG  41911232ul
#define O_END   41911296ul     // ~167.6 MB

// ---------------- dtype detect ----------------
__global__ void k_detect(const void* x, float* flag) {
  int i = threadIdx.x;
  bool bad = false;
  const bf16* xb = (const bf16*)x;
#pragma unroll
  for (int r = 0; r < 4; ++r) {
    float v = b2f(xb[r * 64 + i]);
    if (!(fabsf(v) <= 1e4f)) bad = true;
  }
  bool any = __any(bad);
  if (i == 0) flag[0] = any ? 1.f : 0.f;
}

// ---------------- prep ----------------
__global__ void k_prep(const void* ipw, const void* ipb, const void* c2w, const void* c2b,
                       const void* lw, const void* lb, const void* bng, const void* bnb,
                       const void* xpw, const void* dtw, const void* dtb, const void* alog,
                       const void* dss, const void* ng, const void* nb, const void* opw,
                       const void* opb, float* wb, const float* flag, float* aflag) {
  bool f = flag[0] > 0.5f;
  int i = blockIdx.x * 256 + threadIdx.x;
  if (i < 9216) {
    int r = i / 96, c = i % 96;
    wb[W_INT + c * 96 + r] = ldu(ipw, i, f);
    wb[W_OUTT + c * 96 + r] = ldu(opw, i, f);
  }
  if (i < 96) {
    wb[B_IN + i] = ldu(ipb, i, f); wb[B_C2D + i] = ldu(c2b, i, f); wb[B_LOC + i] = ldu(lb, i, f);
    wb[BN_G + i] = ldu(bng, i, f); wb[BN_B + i] = ldu(bnb, i, f); wb[LN_G + i] = ldu(ng, i, f);
    wb[LN_B + i] = ldu(nb, i, f); wb[B_OUT + i] = ldu(opb, i, f);
  }
  if (i < 864) { wb[W_C2D + i] = ldu(c2w, i, f); wb[W_LOC + i] = ldu(lw, i, f); }
  if (i < 7296) {
    int k = i / 3648, c = (i / 96) % 38, d = i % 96;
    wb[W_XPT + d * 80 + k * 38 + c] = ldu(xpw, i, f);
  }
  if (i < 1152) wb[W_DT + i] = ldu(dtw, i, f);
  if (i < 192) { wb[B_DT + i] = ldu(dtb, i, f); wb[DSOF + i] = ldu(dss, i, f); }
  if (i < 3072) {
    float av = expf(ldu(alog, i, f));
    wb[A2OF + i] = -av * 1.4426950408889634f;
    int n = i % 16;
    if (fabsf(av - (float)(n + 1)) > 1e-3f * (n + 1)) atomicAdd(aflag, 1.f);
  }
}

// ---------------- in_proj (acc-major, d-split x2, 128 thr) ----------------
__global__ __launch_bounds__(128, 4)
void k_inproj(const void* __restrict__ x, const float* __restrict__ wb,
              float* __restrict__ xfeat, const float* __restrict__ flag) {
  int b = blockIdx.x / 36;
  int rest = blockIdx.x % 36;
  int half = rest / 18;
  int l = (rest % 18) * 128 + threadIdx.x;
  float acc[48];
#pragma unroll
  for (int j = 0; j < 48; ++j) acc[j] = wb[B_IN + half * 48 + j];
  bool f = flag[0] > 0.5f;
  if (f) {
    const float* xf = (const float*)x;
#pragma unroll 2
    for (int c = 0; c < 96; ++c) {
      float xc = xf[(b * 96 + c) * LL + l];
      const float* wr = wb + W_INT + c * 96 + half * 48;
#pragma unroll
      for (int j = 0; j < 48; ++j) acc[j] += xc * wr[j];
    }
  } else {
    const bf16* xb = (const bf16*)x;
#pragma unroll 2
    for (int c = 0; c < 96; ++c) {
      float xc = b2f(xb[(b * 96 + c) * LL + l]);
      const float* wr = wb + W_INT + c * 96 + half * 48;
#pragma unroll
      for (int j = 0; j < 48; ++j) acc[j] += xc * wr[j];
    }
  }
#pragma unroll
  for (int j = 0; j < 48; ++j) xfeat[(b * 96 + half * 48 + j) * LL + l] = acc[j];
}

// ---------------- depthwise 3x3 + bias + silu ----------------
__global__ __launch_bounds__(256, 8)
void k_conv_silu(const float* __restrict__ xfeat, const float* __restrict__ wb,
                 float* __restrict__ xconv) {
  int t = blockIdx.x * 256 + threadIdx.x;
  int l = t % LL; int d = (t / LL) % 96; int b = t / (LL * 96);
  int h = l / 48, w = l % 48;
  const float* wr = wb + W_C2D + d * 9;
  const float* src = xfeat + (b * 96 + d) * LL;
  float acc = wb[B_C2D + d];
#pragma unroll
  for (int ki = 0; ki < 3; ++ki) {
    int hh = h + ki - 1; if (hh < 0 || hh >= 48) continue;
#pragma unroll
    for (int kj = 0; kj < 3; ++kj) {
      int ww = w + kj - 1; if (ww < 0 || ww >= 48) continue;
      acc += src[hh * 48 + ww] * wr[ki * 3 + kj];
    }
  }
  xconv[t] = acc / (1.f + expf(-acc));
}

// ---------------- cosine-sim vs center pixel ----------------
__global__ __launch_bounds__(256, 8)
void k_sim(const float* __restrict__ xconv, float* __restrict__ sim) {
  int b = blockIdx.x / 9;
  int l = (blockIdx.x % 9) * 256 + threadIdx.x;
  const float* base = xconv + (size_t)b * 96 * LL;
  float dot = 0, nrm = 0, cn = 0;
  for (int d = 0; d < 96; ++d) {
    float v = base[d * LL + l];
    float c = base[d * LL + 1176];
    dot += v * c; nrm += v * v; cn += c * c;
  }
  float den = fmaxf(sqrtf(nrm), 1e-12f) * fmaxf(sqrtf(cn), 1e-12f);
  sim[b * LL + l] = dot / den;
}

// ---------------- per-batch stable argsort desc (bitonic) ----------------
__global__ void k_sort(const float* __restrict__ sim, int* __restrict__ sidx) {
  __shared__ unsigned long long key[4096];
  int b = blockIdx.x;
  for (int i = threadIdx.x; i < 4096; i += 1024) {
    unsigned long long kv = ~0ull;
    if (i < LL) {
      unsigned u = __float_as_uint(sim[b * LL + i]);
      u = (u >> 31) ? ~u : (u | 0x80000000u);
      kv = (((unsigned long long)(~u)) << 32) | (unsigned)i;
    }
    key[i] = kv;
  }
  __syncthreads();
  for (int k = 2; k <= 4096; k <<= 1)
    for (int j = k >> 1; j > 0; j >>= 1) {
      for (int i = threadIdx.x; i < 4096; i += 1024) {
        int ij = i ^ j;
        if (ij > i) {
          unsigned long long a = key[i], c = key[ij];
          bool up = ((i & k) == 0);
          if ((a > c) == up) { key[i] = c; key[ij] = a; }
        }
      }
      __syncthreads();
    }
  for (int i = threadIdx.x; i < LL; i += 1024) sidx[b * LL + i] = (int)(key[i] & 0xffffffffu);
}

// ---------------- gather to d-major: xstd[b][d][l'] = xconv[b][d][sidx[l']] ----------------
__global__ __launch_bounds__(256, 8)
void k_gatherd(const float* __restrict__ xconv, const int* __restrict__ sidx,
               float* __restrict__ xstd) {
  int t = blockIdx.x * 256 + threadIdx.x;
  int l = t % LL; int d = (t / LL) % 96; int b = t / (LL * 96);
  int p = sidx[b * LL + l];
  xstd[t] = xconv[((size_t)b * 96 + d) * LL + p];
}

// ---------------- transpose d-major -> l-major ----------------
__global__ __launch_bounds__(256, 4)
void k_tr_dl(const float* __restrict__ in, float* __restrict__ out) {
  __shared__ float tile[64 * 97];
  int b = blockIdx.x / 36;
  int l0 = (blockIdx.x % 36) * 64;
#pragma unroll
  for (int it = 0; it < 24; ++it) {
    int idx = it * 256 + threadIdx.x;
    int d = idx / 64, j = idx % 64;
    tile[j * 97 + d] = in[((size_t)b * 96 + d) * LL + l0 + j];
  }
  __syncthreads();
#pragma unroll
  for (int it = 0; it < 24; ++it) {
    int idx = it * 256 + threadIdx.x;
    int r = idx / 96, c = idx % 96;
    out[((size_t)b * LL + l0 + r) * 96 + c] = tile[r * 97 + c];
  }
}

// ---------------- transpose l-major -> d-major ----------------
__global__ __launch_bounds__(256, 4)
void k_tr_ld(const float* __restrict__ in, float* __restrict__ out) {
  __shared__ float tile[64 * 97];
  int b = blockIdx.x / 36;
  int l0 = (blockIdx.x % 36) * 64;
#pragma unroll
  for (int it = 0; it < 24; ++it) {
    int idx = it * 256 + threadIdx.x;
    int r = idx / 96, c = idx % 96;
    tile[r * 97 + c] = in[((size_t)b * LL + l0 + r) * 96 + c];
  }
  __syncthreads();
#pragma unroll
  for (int it = 0; it < 24; ++it) {
    int idx = it * 256 + threadIdx.x;
    int d = idx / 64, j = idx % 64;
    out[((size_t)b * 96 + d) * LL + l0 + j] = tile[j * 97 + d];
  }
}

// ---------------- x_dbl for one direction (acc-major, 128 thr) ----------------
template <int KSEL>
__global__ __launch_bounds__(128, 4)
void k_xdbl(const float* __restrict__ xstd, const float* __restrict__ wb,
            float* __restrict__ rbuf, float* __restrict__ bc) {
  int b = blockIdx.x / 18;
  int l = (blockIdx.x % 18) * 128 + threadIdx.x;
  float acc[38];
#pragma unroll
  for (int j = 0; j < 38; ++j) acc[j] = 0.f;
#pragma unroll 2
  for (int c = 0; c < 96; ++c) {
    float xc = xstd[((size_t)b * 96 + c) * LL + l];
    const float* wr = wb + W_XPT + c * 80 + KSEL * 38;   // uniform -> s_load
#pragma unroll
    for (int j = 0; j < 38; ++j) acc[j] += xc * wr[j];
  }
  int lout = KSEL ? (LL - 1 - l) : l;
  float4* r4 = (float4*)(rbuf + ((size_t)(b * 2 + KSEL) * LL + lout) * 8);
  r4[0] = make_float4(acc[0], acc[1], acc[2], acc[3]);
  r4[1] = make_float4(acc[4], acc[5], 0.f, 0.f);
  float4* b4 = (float4*)(bc + ((size_t)(b * 2 + KSEL) * LL + lout) * 32);
#pragma unroll
  for (int i = 0; i < 8; ++i)
    b4[i] = make_float4(acc[6 + 4 * i], acc[7 + 4 * i], acc[8 + 4 * i], acc[9 + 4 * i]);
}

// ---------------- scan pass 1: 32-step segments, LDS-staged bc/rr ----------------
__global__ __launch_bounds__(192, 4)
void k_scan1(const float* __restrict__ rbuf, const float* __restrict__ bc,
             const float* __restrict__ xst, const float* __restrict__ wb,
             float* __restrict__ dsum, float* __restrict__ hend,
             const float* __restrict__ aflag) {
  __shared__ float sbc[2][1024];
  __shared__ float srr[2][256];
  int sub = threadIdx.x / 96;
  int tid = threadIdx.x - sub * 96;
  int unit = blockIdx.x * 2 + sub;             // b*144 + k*72 + s
  int s = unit % 72; int k = (unit / 72) % 2; int b = unit / 144;
  int lbase = (b * 2 + k) * LL + s * 32;
  {
    const float4* bsrc = (const float4*)(bc + (size_t)lbase * 32);
    float4* bdst = (float4*)sbc[sub];
    for (int i = tid; i < 256; i += 96) bdst[i] = bsrc[i];
    const float4* rsrc = (const float4*)(rbuf + (size_t)lbase * 8);
    float4* rdst = (float4*)srr[sub];
    if (tid < 64) rdst[tid] = rsrc[tid];
  }
  __syncthreads();
  int d = tid;
  float wd[6];
#pragma unroll
  for (int j = 0; j < 6; ++j) wd[j] = wb[W_DT + (k * 96 + d) * 6 + j];
  float bd = wb[B_DT + k * 96 + d];
  float h[16];
#pragma unroll
  for (int n = 0; n < 16; ++n) h[n] = 0.f;
  float ds = 0.f;
  long long lk0 = k ? (LL - 1 - s * 32) : (s * 32);
  long long stp = k ? -96 : 96;
  const float* xp = xst + (size_t)b * LL * 96 + lk0 * 96 + d;
  bool fast = (aflag[0] == 0.f);
  if (fast) {
#pragma unroll 4
    for (int t = 0; t < 32; ++t) {
      float xv = *xp; xp += stp;
      const float* rr = &srr[sub][t * 8];
      float a = bd + rr[0] * wd[0] + rr[1] * wd[1] + rr[2] * wd[2]
                   + rr[3] * wd[3] + rr[4] * wd[4] + rr[5] * wd[5];
      float ea = expf(a);
      float dtv = (a > 20.f) ? a : log1pf(ea);
      ds += dtv;
      float dtx = dtv * xv;
      const float* bcl = &sbc[sub][t * 32];
      float p1 = 1.f / (1.f + ea);
      float p2 = p1 * p1, p3 = p2 * p1, p4 = p2 * p2, p5 = p4 * p1, p6 = p4 * p2,
            p7 = p4 * p3, p8 = p4 * p4, p9 = p8 * p1, p10 = p8 * p2, p11 = p8 * p3,
            p12 = p8 * p4, p13 = p8 * p5, p14 = p8 * p6, p15 = p8 * p7, p16 = p8 * p8;
      h[0] = p1 * h[0] + dtx * bcl[0];   h[1] = p2 * h[1] + dtx * bcl[1];
      h[2] = p3 * h[2] + dtx * bcl[2];   h[3] = p4 * h[3] + dtx * bcl[3];
      h[4] = p5 * h[4] + dtx * bcl[4];   h[5] = p6 * h[5] + dtx * bcl[5];
      h[6] = p7 * h[6] + dtx * bcl[6];   h[7] = p8 * h[7] + dtx * bcl[7];
      h[8] = p9 * h[8] + dtx * bcl[8];   h[9] = p10 * h[9] + dtx * bcl[9];
      h[10] = p11 * h[10] + dtx * bcl[10]; h[11] = p12 * h[11] + dtx * bcl[11];
      h[12] = p13 * h[12] + dtx * bcl[12]; h[13] = p14 * h[13] + dtx * bcl[13];
      h[14] = p15 * h[14] + dtx * bcl[14]; h[15] = p16 * h[15] + dtx * bcl[15];
    }
  } else {
    float a2[16];
#pragma unroll
    for (int n = 0; n < 16; ++n) a2[n] = wb[A2OF + (k * 96 + d) * 16 + n];
#pragma unroll 4
    for (int t = 0; t < 32; ++t) {
      float xv = *xp; xp += stp;
      const float* rr = &srr[sub][t * 8];
      float a = bd + rr[0] * wd[0] + rr[1] * wd[1] + rr[2] * wd[2]
                   + rr[3] * wd[3] + rr[4] * wd[4] + rr[5] * wd[5];
      float dtv = (a > 20.f) ? a : log1pf(expf(a));
      ds += dtv;
      float dtx = dtv * xv;
      const float* bcl = &sbc[sub][t * 32];
#pragma unroll
      for (int n = 0; n < 16; ++n) h[n] = exp2f(dtv * a2[n]) * h[n] + dtx * bcl[n];
    }
  }
  dsum[((b * 2 + k) * 96 + d) * NSEG + s] = ds;
  float4* ho = (float4*)(hend + (((size_t)(b * 2 + k) * NSEG + s) * 96 + d) * 16);
  ho[0] = make_float4(h[0], h[1], h[2], h[3]);
  ho[1] = make_float4(h[4], h[5], h[6], h[7]);
  ho[2] = make_float4(h[8], h[9], h[10], h[11]);
  ho[3] = make_float4(h[12], h[13], h[14], h[15]);
}

// ---------------- scan pass 2: stitch 72 segments ----------------
__global__ __launch_bounds__(256, 4)
void k_scan2(const float* __restrict__ dsum, const float* __restrict__ hend,
             const float* __restrict__ wb, float* __restrict__ hstart) {
  int t = blockIdx.x * 256 + threadIdx.x;
  int n = t % 16; int d = (t / 16) % 96; int k = (t / 1536) % 2; int b = t / 3072;
  float a2 = wb[A2OF + (k * 96 + d) * 16 + n];
  float h = 0.f;
  int rowd = ((b * 2 + k) * 96 + d) * NSEG;
  for (int s = 0; s < NSEG; ++s) {
    size_t idx = (((size_t)(b * 2 + k) * NSEG + s) * 96 + d) * 16 + n;
    hstart[idx] = h;
    h = exp2f(a2 * dsum[rowd + s]) * h + hend[idx];
  }
}

// ---------------- scan3 + combine + LN (32-row tiles, staged) ----------------
__global__ __launch_bounds__(192, 4)
void k_scan3ln(const float* __restrict__ rbuf, const float* __restrict__ bc,
               const float* __restrict__ xst, const float* __restrict__ wb,
               const float* __restrict__ hstart, const int* __restrict__ sidx,
               float* __restrict__ ymlm, const float* __restrict__ aflag) {
  __shared__ float yA[32 * 97];
  __shared__ float yB[32 * 97];
  __shared__ float sbc[2][1024];
  __shared__ float srr[2][256];
  __shared__ float smu[32], srs[32];
  int b = blockIdx.x / NSEG;
  int u = blockIdx.x % NSEG;
  int t = threadIdx.x;
  int sub = t / 96;                      // sub==k
  int d = t - sub * 96;
  int k = sub;
  int seg = sub ? (NSEG - 1 - u) : u;
  int lbase = (b * 2 + k) * LL + seg * 32;
  {
    const float4* bsrc = (const float4*)(bc + (size_t)lbase * 32);
    float4* bdst = (float4*)sbc[sub];
    for (int i = d; i < 256; i += 96) bdst[i] = bsrc[i];
    const float4* rsrc = (const float4*)(rbuf + (size_t)lbase * 8);
    float4* rdst = (float4*)srr[sub];
    if (d < 64) rdst[d] = rsrc[d];
  }
  __syncthreads();
  {
    float* yacc = sub ? yB : yA;
    float wd[6];
#pragma unroll
    for (int j = 0; j < 6; ++j) wd[j] = wb[W_DT + (k * 96 + d) * 6 + j];
    float bd = wb[B_DT + k * 96 + d];
    float Dv = wb[DSOF + k * 96 + d];
    float h[16];
    const float* hi = hstart + (((size_t)(b * 2 + k) * NSEG + seg) * 96 + d) * 16;
#pragma unroll
    for (int n = 0; n < 16; ++n) h[n] = hi[n];
    long long lk0 = k ? (LL - 1 - seg * 32) : (seg * 32);
    long long stp = k ? -96 : 96;
    const float* xp = xst + (size_t)b * LL * 96 + lk0 * 96 + d;
    bool fast = (aflag[0] == 0.f);
    if (fast) {
#pragma unroll 4
      for (int i = 0; i < 32; ++i) {
        float xv = *xp; xp += stp;
        const float* rr = &srr[sub][i * 8];
        float a = bd + rr[0] * wd[0] + rr[1] * wd[1] + rr[2] * wd[2]
                     + rr[3] * wd[3] + rr[4] * wd[4] + rr[5] * wd[5];
        float ea = expf(a);
        float dtv = (a > 20.f) ? a : log1pf(ea);
        float dtx = dtv * xv;
        const float* bcl = &sbc[sub][i * 32];
        float p1 = 1.f / (1.f + ea);
        float p2 = p1 * p1, p3 = p2 * p1, p4 = p2 * p2, p5 = p4 * p1, p6 = p4 * p2,
              p7 = p4 * p3, p8 = p4 * p4, p9 = p8 * p1, p10 = p8 * p2, p11 = p8 * p3,
              p12 = p8 * p4, p13 = p8 * p5, p14 = p8 * p6, p15 = p8 * p7, p16 = p8 * p8;
        float y;
        h[0] = p1 * h[0] + dtx * bcl[0];   y  = h[0] * bcl[16];
        h[1] = p2 * h[1] + dtx * bcl[1];   y += h[1] * bcl[17];
        h[2] = p3 * h[2] + dtx * bcl[2];   y += h[2] * bcl[18];
        h[3] = p4 * h[3] + dtx * bcl[3];   y += h[3] * bcl[19];
        h[4] = p5 * h[4] + dtx * bcl[4];   y += h[4] * bcl[20];
        h[5] = p6 * h[5] + dtx * bcl[5];   y += h[5] * bcl[21];
        h[6] = p7 * h[6] + dtx * bcl[6];   y += h[6] * bcl[22];
        h[7] = p8 * h[7] + dtx * bcl[7];   y += h[7] * bcl[23];
        h[8] = p9 * h[8] + dtx * bcl[8];   y += h[8] * bcl[24];
        h[9] = p10 * h[9] + dtx * bcl[9];  y += h[9] * bcl[25];
        h[10] = p11 * h[10] + dtx * bcl[10]; y += h[10] * bcl[26];
        h[11] = p12 * h[11] + dtx * bcl[11]; y += h[11] * bcl[27];
        h[12] = p13 * h[12] + dtx * bcl[12]; y += h[12] * bcl[28];
        h[13] = p14 * h[13] + dtx * bcl[13]; y += h[13] * bcl[29];
        h[14] = p15 * h[14] + dtx * bcl[14]; y += h[14] * bcl[30];
        h[15] = p16 * h[15] + dtx * bcl[15]; y += h[15] * bcl[31];
        int qloc = k ? (31 - i) : i;
        yacc[qloc * 97 + d] = y + Dv * xv;
      }
    } else {
      float a2[16];
#pragma unroll
      for (int n = 0; n < 16; ++n) a2[n] = wb[A2OF + (k * 96 + d) * 16 + n];
#pragma unroll 4
      for (int i = 0; i < 32; ++i) {
        float xv = *xp; xp += stp;
        const float* rr = &srr[sub][i * 8];
        float a = bd + rr[0] * wd[0] + rr[1] * wd[1] + rr[2] * wd[2]
                     + rr[3] * wd[3] + rr[4] * wd[4] + rr[5] * wd[5];
        float dtv = (a > 20.f) ? a : log1pf(expf(a));
        float dtx = dtv * xv;
        const float* bcl = &sbc[sub][i * 32];
        float y = 0.f;
#pragma unroll
        for (int n = 0; n < 16; ++n) {
          h[n] = exp2f(dtv * a2[n]) * h[n] + dtx * bcl[n];
          y += h[n] * bcl[16 + n];
        }
        int qloc = k ? (31 - i) : i;
        yacc[qloc * 97 + d] = y + Dv * xv;
      }
    }
  }
  __syncthreads();
  if (t < 32) {
    float sum = 0, ss = 0;
#pragma unroll
    for (int dd = 0; dd < 96; ++dd) {
      float v = yA[t * 97 + dd] + yB[t * 97 + dd];
      sum += v; ss += v * v;
    }
    float mu = sum * (1.f / 96.f);
    float var = ss * (1.f / 96.f) - mu * mu;
    smu[t] = mu;
    srs[t] = rsqrtf(var + 1e-5f);
  }
  __syncthreads();
  {
    int r = t / 6, c0 = (t % 6) * 16;
    int q = u * 32 + r;
    int p = sidx[b * LL + q];
    float mu = smu[r], rs = srs[r];
    float tmp[16];
#pragma unroll
    for (int j = 0; j < 16; ++j) {
      int dd = c0 + j;
      tmp[j] = (yA[r * 97 + dd] + yB[r * 97 + dd] - mu) * rs * wb[LN_G + dd] + wb[LN_B + dd];
    }
    float4* o4 = (float4*)(ymlm + ((size_t)b * LL + p) * 96 + c0);
    o4[0] = make_float4(tmp[0], tmp[1], tmp[2], tmp[3]);
    o4[1] = make_float4(tmp[4], tmp[5], tmp[6], tmp[7]);
    o4[2] = make_float4(tmp[8], tmp[9], tmp[10], tmp[11]);
    o4[3] = make_float4(tmp[12], tmp[13], tmp[14], tmp[15]);
  }
}

// ---------------- local conv + bias + BN stats (fused) ----------------
__global__ __launch_bounds__(256, 8)
void k_convlc_bn(const float* __restrict__ xconv, const float* __restrict__ wb,
                 float* __restrict__ lcbuf, float* __restrict__ stats) {
  int bd = blockIdx.x;
  int b = bd / 96, d = bd % 96;
  const float* src = xconv + (size_t)(b * 96 + d) * LL;
  const float* wr = wb + W_LOC + d * 9;
  float bias = wb[B_LOC + d];
  float s1 = 0, s2 = 0;
  for (int l = threadIdx.x; l < LL; l += 256) {
    int h = l / 48, w = l % 48;
    float acc = bias;
#pragma unroll
    for (int ki = 0; ki < 3; ++ki) {
      int hh = h + ki - 1; if (hh < 0 || hh >= 48) continue;
#pragma unroll
      for (int kj = 0; kj < 3; ++kj) {
        int ww = w + kj - 1; if (ww < 0 || ww >= 48) continue;
        acc += src[hh * 48 + ww] * wr[ki * 3 + kj];
      }
    }
    lcbuf[(size_t)(b * 96 + d) * LL + l] = acc;
    s1 += acc; s2 += acc * acc;
  }
  __shared__ float r1[256], r2[256];
  r1[threadIdx.x] = s1; r2[threadIdx.x] = s2; __syncthreads();
  for (int o = 128; o > 0; o >>= 1) {
    if (threadIdx.x < o) { r1[threadIdx.x] += r1[threadIdx.x + o]; r2[threadIdx.x] += r2[threadIdx.x + o]; }
    __syncthreads();
  }
  if (threadIdx.x == 0) { atomicAdd(&stats[d], r1[0]); atomicAdd(&stats[96 + d], r2[0]); }
}

__global__ void k_bnfin(const float* __restrict__ stats, const float* __restrict__ wb,
                        float* __restrict__ scsh) {
  int d = threadIdx.x; if (d >= 96) return;
  float mean = stats[d] * (1.f / 73728.f);
  float var = stats[96 + d] * (1.f / 73728.f) - mean * mean;
  float sc = wb[BN_G + d] * rsqrtf(var + 1e-5f);
  scsh[d] = sc; scsh[96 + d] = wb[BN_B + d] - mean * sc;
}

// ---------------- final (acc-major, c-split x2, 128 thr) ----------------
__global__ __launch_bounds__(128, 4)
void k_final(const float* __restrict__ lcbuf, const float* __restrict__ ymdm,
             const float* __restrict__ wb, const float* __restrict__ scsh,
             void* __restrict__ out, const float* __restrict__ flag) {
  int b = blockIdx.x / 36;
  int rest = blockIdx.x % 36;
  int half = rest / 18;
  int l = (rest % 18) * 128 + threadIdx.x;
  float acc[48];
#pragma unroll
  for (int j = 0; j < 48; ++j) acc[j] = wb[B_OUT + half * 48 + j];
#pragma unroll 2
  for (int d = 0; d < 96; ++d) {
    float lc = lcbuf[((size_t)b * 96 + d) * LL + l] * scsh[d] + scsh[96 + d];
    float vd = lc / (1.f + expf(-lc)) + ymdm[((size_t)b * 96 + d) * LL + l];
    const float* wr = wb + W_OUTT + d * 96 + half * 48;   // uniform -> s_load
#pragma unroll
    for (int j = 0; j < 48; ++j) acc[j] += vd * wr[j];
  }
  bool f = flag[0] > 0.5f;
  if (f) {
    float* of = (float*)out;
#pragma unroll
    for (int j = 0; j < 48; ++j) of[(b * 96 + half * 48 + j) * LL + l] = acc[j];
  } else {
    bf16* ob = (bf16*)out;
#pragma unroll
    for (int j = 0; j < 48; ++j) ob[(b * 96 + half * 48 + j) * LL + l] = __float2bfloat16(acc[j]);
  }
}

extern "C" void kernel_launch(void* const* d_in, const int* in_sizes, int n_in,
                              void* d_out, int out_size, void* d_ws, size_t ws_size,
                              hipStream_t stream) {
  if (ws_size < O_END * sizeof(float)) return;
  float* ws = (float*)d_ws;
  float* wb    = ws + O_WBUF;
  float* xfeat = ws + O_XFEAT;
  float* xconv = ws + O_XCONV;
  float* sim   = ws + O_SIM;
  int*   sidx  = (int*)(ws + O_SIDX);
  float* xst   = ws + O_XST;
  float* xstd  = ws + O_XSTD;
  float* rbuf  = ws + O_RBUF;
  float* bc    = ws + O_BC;
  float* dsum  = ws + O_DSUM;
  float* ymlm  = ws + O_YMLM;
  float* stats = ws + O_STATS;
  float* aflag = ws + O_AFLG;
  float* scsh  = ws + O_SCSH;
  float* flag  = ws + O_FLAG;
  float* hend   = xfeat;   // xfeat dead after conv_silu
  float* hstart = xstd;    // xstd dead after xdbl
  float* ymdm   = xfeat;   // hend dead after scan2 read / scan3ln
  float* lcbuf  = xst;     // xst dead after scan3ln

  hipMemsetAsync(stats, 0, 256 * sizeof(float), stream);   // stats + aflag
  k_detect<<<1, 64, 0, stream>>>(d_in[0], flag);
  k_prep<<<36, 256, 0, stream>>>(
      d_in[1], d_in[2], d_in[5], d_in[6], d_in[7], d_in[8], d_in[9], d_in[10],
      d_in[11], d_in[12], d_in[13], d_in[14], d_in[15], d_in[16], d_in[17], d_in[18],
      d_in[19], wb, flag, aflag);
  k_inproj<<<1152, 128, 0, stream>>>(d_in[0], wb, xfeat, flag);
  k_conv_silu<<<27648, 256, 0, stream>>>(xfeat, wb, xconv);
  k_sim<<<288, 256, 0, stream>>>(xconv, sim);
  k_sort<<<32, 1024, 0, stream>>>(sim, sidx);
  k_gatherd<<<27648, 256, 0, stream>>>(xconv, sidx, xstd);
  k_tr_dl<<<1152, 256, 0, stream>>>(xstd, xst);
  k_xdbl<0><<<576, 128, 0, stream>>>(xstd, wb, rbuf, bc);
  k_xdbl<1><<<576, 128, 0, stream>>>(xstd, wb, rbuf, bc);
  k_scan1<<<2304, 192, 0, stream>>>(rbuf, bc, xst, wb, dsum, hend, aflag);
  k_scan2<<<384, 256, 0, stream>>>(dsum, hend, wb, hstart);
  k_scan3ln<<<2304, 192, 0, stream>>>(rbuf, bc, xst, wb, hstart, sidx, ymlm, aflag);
  k_tr_ld<<<1152, 256, 0, stream>>>(ymlm, ymdm);
  k_convlc_bn<<<3072, 256, 0, stream>>>(xconv, wb, lcbuf, stats);
  k_bnfin<<<1, 96, 0, stream>>>(stats, wb, scsh);
  k_final<<<1152, 128, 0, stream>>>(lcbuf, ymdm, wb, scsh, d_out, flag);
}